// Round 1
// baseline (966.578 us; speedup 1.0000x reference)
//
#include <hip/hip_runtime.h>

#define B_ 2
#define N_ 2048
#define E_ 64
#define FIN_ 18
#define ADJ_CAP 128
#define A2_CAP 1024
#define ROWS 8

__device__ __forceinline__ float wave_sum(float v) {
  #pragma unroll
  for (int o = 32; o > 0; o >>= 1) v += __shfl_xor(v, o);
  return v;
}
__device__ __forceinline__ float wave_max(float v) {
  #pragma unroll
  for (int o = 32; o > 0; o >>= 1) v = fmaxf(v, __shfl_xor(v, o));
  return v;
}

// ---------------- init accumulators ----------------
__global__ void k_init(float* accum) {
  if (threadIdx.x < 8) accum[threadIdx.x] = 0.f;
}

// ---------------- build CSR from neighborhoods (K=2,B,N,N) ----------------
__global__ void k_csr(const float* __restrict__ nbhd, int* __restrict__ adj_idx,
                      int* __restrict__ adj_cnt, int* __restrict__ a2_idx,
                      int* __restrict__ a2_cnt) {
  int wid = blockIdx.x * 4 + (threadIdx.x >> 6);  // 0 .. 2*B*N-1
  int lane = threadIdx.x & 63;
  int k = wid / (B_ * N_);
  int rem = wid - k * (B_ * N_);  // b*N + i
  const float* row = nbhd + ((size_t)k * (B_ * N_) + rem) * N_;
  int cap = (k == 0) ? ADJ_CAP : A2_CAP;
  int* idx = ((k == 0) ? adj_idx : a2_idx) + (size_t)rem * cap;
  int* cntp = ((k == 0) ? adj_cnt : a2_cnt) + rem;
  int cnt = 0;
  for (int j0 = 0; j0 < N_; j0 += 64) {
    float v = row[j0 + lane];
    bool p = v > 0.f;
    unsigned long long m = __ballot(p);
    int pre = __popcll(m & ((1ull << lane) - 1ull));
    if (p) { int pos = cnt + pre; if (pos < cap) idx[pos] = j0 + lane; }
    cnt += __popcll(m);
  }
  if (lane == 0) *cntp = (cnt < cap) ? cnt : cap;
}

// ---------------- encoder: h = tanh(tanh(x@W0+b0)@W1+b1) ----------------
__global__ void k_enc(const float* __restrict__ emb, const float* __restrict__ feat,
                      const float* __restrict__ W0, const float* __restrict__ b0,
                      const float* __restrict__ W1, const float* __restrict__ b1,
                      float* __restrict__ h) {
  int j = threadIdx.x;  // 64
  int row0 = blockIdx.x * ROWS;
  __shared__ float X[ROWS][FIN_];
  __shared__ float HID[ROWS][64];
  for (int t = j; t < ROWS * FIN_; t += 64) {
    int r = t / FIN_, d = t % FIN_;
    int row = row0 + r;
    X[r][d] = (d < 16) ? emb[(size_t)row * 16 + d] : feat[(size_t)row * 2 + (d - 16)];
  }
  __syncthreads();
  float acc[ROWS];
  #pragma unroll
  for (int r = 0; r < ROWS; r++) acc[r] = b0[j];
  for (int d = 0; d < FIN_; d++) {
    float w = W0[d * 64 + j];
    #pragma unroll
    for (int r = 0; r < ROWS; r++) acc[r] += X[r][d] * w;
  }
  #pragma unroll
  for (int r = 0; r < ROWS; r++) HID[r][j] = tanhf(acc[r]);
  __syncthreads();
  float acc2[ROWS];
  #pragma unroll
  for (int r = 0; r < ROWS; r++) acc2[r] = b1[j];
  for (int d = 0; d < 64; d++) {
    float w = W1[d * 64 + j];
    #pragma unroll
    for (int r = 0; r < ROWS; r++) acc2[r] += HID[r][d] * w;
  }
  #pragma unroll
  for (int r = 0; r < ROWS; r++) h[(size_t)(row0 + r) * 64 + j] = tanhf(acc2[r]);
}

// ---------------- z = h@attn_W[head], s_src, s_dst ----------------
__global__ void k_z(const float* __restrict__ h, const float* __restrict__ attn_W,
                    const float* __restrict__ a_src, const float* __restrict__ a_dst,
                    float* __restrict__ z, float* __restrict__ ssrc, float* __restrict__ sdst) {
  int tid = threadIdx.x;  // 128
  int head = tid >> 6, j = tid & 63;
  int row0 = blockIdx.x * ROWS;
  __shared__ float HR[ROWS][64];
  for (int t = tid; t < ROWS * 64; t += 128) HR[t >> 6][t & 63] = h[(size_t)row0 * 64 + t];
  __syncthreads();
  float acc[ROWS];
  #pragma unroll
  for (int r = 0; r < ROWS; r++) acc[r] = 0.f;
  const float* W = attn_W + head * 64 * 64;
  for (int d = 0; d < 64; d++) {
    float w = W[d * 64 + j];
    #pragma unroll
    for (int r = 0; r < ROWS; r++) acc[r] += HR[r][d] * w;
  }
  float as = a_src[head * 64 + j], ad = a_dst[head * 64 + j];
  #pragma unroll
  for (int r = 0; r < ROWS; r++) {
    float zv = acc[r];
    z[((size_t)head * (B_ * N_) + row0 + r) * 64 + j] = zv;
    float rs = wave_sum(zv * as);
    float rd = wave_sum(zv * ad);
    if (j == 0) {
      ssrc[head * (B_ * N_) + row0 + r] = rs;
      sdst[head * (B_ * N_) + row0 + r] = rd;
    }
  }
}

// ---------------- sparse masked-softmax attention aggregate ----------------
__global__ void k_agg(const int* __restrict__ adj_idx, const int* __restrict__ adj_cnt,
                      const int* __restrict__ a2_idx, const int* __restrict__ a2_cnt,
                      const float* __restrict__ z, const float* __restrict__ ssrc,
                      const float* __restrict__ sdst, float* __restrict__ aggs) {
  int k = blockIdx.x & 1;
  int row = blockIdx.x >> 1;  // b*N+i
  int lane = threadIdx.x;     // 64
  int b = row >> 11;
  int cap = (k == 0) ? ADJ_CAP : A2_CAP;
  const int* idx = ((k == 0) ? adj_idx : a2_idx) + (size_t)row * cap;
  int cnt = ((k == 0) ? adj_cnt : a2_cnt)[row];
  __shared__ float SC0[A2_CAP], SC1[A2_CAP];
  __shared__ int COL[A2_CAP];
  float ss0 = ssrc[row], ss1 = ssrc[B_ * N_ + row];
  const float* sd0 = sdst + b * N_;
  const float* sd1 = sdst + B_ * N_ + b * N_;
  float m0 = -1e30f, m1 = -1e30f;
  for (int t = lane; t < cnt; t += 64) {
    int c = idx[t];
    COL[t] = c;
    float s0 = tanhf(ss0 + sd0[c]);
    float s1 = tanhf(ss1 + sd1[c]);
    SC0[t] = s0; SC1[t] = s1;
    m0 = fmaxf(m0, s0); m1 = fmaxf(m1, s1);
  }
  m0 = wave_max(m0); m1 = wave_max(m1);
  float sum0 = 0.f, sum1 = 0.f;
  for (int t = lane; t < cnt; t += 64) {  // same lanes as wrote -> no sync needed yet
    float e0 = __expf(SC0[t] - m0);
    float e1 = __expf(SC1[t] - m1);
    SC0[t] = e0; SC1[t] = e1;
    sum0 += e0; sum1 += e1;
  }
  sum0 = wave_sum(sum0); sum1 = wave_sum(sum1);
  float inv0 = (sum0 > 0.f) ? 1.f / sum0 : 0.f;
  float inv1 = (sum1 > 0.f) ? 1.f / sum1 : 0.f;
  __syncthreads();
  const float* z0 = z + ((size_t)b * N_) * 64;
  const float* z1 = z + ((size_t)(B_ * N_) + b * N_) * 64;
  float acc0 = 0.f, acc1 = 0.f;
  #pragma unroll 4
  for (int t = 0; t < cnt; t++) {
    int c = COL[t];
    float a0 = SC0[t] * inv0, a1 = SC1[t] * inv1;
    acc0 += a0 * z0[(size_t)c * 64 + lane];
    acc1 += a1 * z1[(size_t)c * 64 + lane];
  }
  aggs[((size_t)row * 2 + k) * 64 + lane] = tanhf(0.5f * (acc0 + acc1));
}

// ---------------- nbr-softmax combine + GRU ----------------
__global__ void k_comb(const float* __restrict__ aggs, const float* __restrict__ nbr_q,
                       const float* __restrict__ gru_W, const float* __restrict__ gru_U,
                       const float* __restrict__ gru_b, float* __restrict__ h) {
  int tid = threadIdx.x;  // 128
  int w = tid >> 6, j = tid & 63;
  int row0 = blockIdx.x * ROWS;
  __shared__ float NXT[ROWS][64], HROW[ROWS][64], RG[ROWS][64], ZG[ROWS][64];
  for (int t = tid; t < ROWS * 64; t += 128) HROW[t >> 6][t & 63] = h[(size_t)row0 * 64 + t];
  float q = nbr_q[j];
  for (int r = w * (ROWS / 2); r < (w + 1) * (ROWS / 2); r++) {
    float a0 = aggs[((size_t)(row0 + r) * 2 + 0) * 64 + j];
    float a1 = aggs[((size_t)(row0 + r) * 2 + 1) * 64 + j];
    float t0 = tanhf(wave_sum(a0 * q));
    float t1 = tanhf(wave_sum(a1 * q));
    float mx = fmaxf(t0, t1);
    float e0 = __expf(t0 - mx), e1 = __expf(t1 - mx);
    float inv = 1.f / (e0 + e1);
    NXT[r][j] = (e0 * a0 + e1 * a1) * inv;
  }
  __syncthreads();
  {
    float acc[ROWS];
    #pragma unroll
    for (int r = 0; r < ROWS; r++) acc[r] = gru_b[tid];
    for (int d = 0; d < 64; d++) {
      float wW = gru_W[d * 192 + tid];
      float wU = gru_U[d * 192 + tid];
      #pragma unroll
      for (int r = 0; r < ROWS; r++) acc[r] += NXT[r][d] * wW + HROW[r][d] * wU;
    }
    #pragma unroll
    for (int r = 0; r < ROWS; r++) {
      float zr = 1.f / (1.f + __expf(-acc[r]));
      if (tid < 64) ZG[r][tid] = zr; else RG[r][tid - 64] = zr;
    }
  }
  __syncthreads();
  if (tid < 64) {
    int col = 128 + tid;
    float acc[ROWS];
    #pragma unroll
    for (int r = 0; r < ROWS; r++) acc[r] = gru_b[col];
    for (int d = 0; d < 64; d++) {
      float wW = gru_W[d * 192 + col];
      float wU = gru_U[d * 192 + col];
      #pragma unroll
      for (int r = 0; r < ROWS; r++) acc[r] += NXT[r][d] * wW + (RG[r][d] * HROW[r][d]) * wU;
    }
    #pragma unroll
    for (int r = 0; r < ROWS; r++) {
      float ht = tanhf(acc[r]);
      float zg = ZG[r][tid];
      h[(size_t)(row0 + r) * 64 + tid] = (1.f - zg) * HROW[r][tid] + zg * ht;
    }
  }
}

// ---------------- decoder + dual heads (+ dual_demand) ----------------
__global__ void k_dec(const float* __restrict__ h, const float* __restrict__ dW0,
                      const float* __restrict__ db0, const float* __restrict__ dW1,
                      const float* __restrict__ db1, const float* __restrict__ uW0,
                      const float* __restrict__ ub0, const float* __restrict__ uW1,
                      const float* __restrict__ ub1, const float* __restrict__ demands,
                      float* __restrict__ nw, float* __restrict__ dv, float* accum) {
  int j = threadIdx.x;  // 64
  int row0 = blockIdx.x * ROWS;
  __shared__ float HROW[ROWS][64];
  for (int t = j; t < ROWS * 64; t += 64) HROW[t >> 6][t & 63] = h[(size_t)row0 * 64 + t];
  __syncthreads();
  float hd[ROWS], hu[ROWS];
  #pragma unroll
  for (int r = 0; r < ROWS; r++) { hd[r] = db0[j]; hu[r] = ub0[j]; }
  for (int d = 0; d < 64; d++) {
    float w0 = dW0[d * 64 + j], u0 = uW0[d * 64 + j];
    #pragma unroll
    for (int r = 0; r < ROWS; r++) { hd[r] += HROW[r][d] * w0; hu[r] += HROW[r][d] * u0; }
  }
  float w1 = dW1[j], u1 = uW1[j];
  float ddl = 0.f;
  #pragma unroll
  for (int r = 0; r < ROWS; r++) {
    float a = wave_sum(tanhf(hd[r]) * w1);
    float bb = wave_sum(tanhf(hu[r]) * u1);
    if (j == 0) {
      int row = row0 + r;
      float nwv = a + db1[0], dvv = bb + ub1[0];
      nw[row] = nwv; dv[row] = dvv;
      ddl += dvv * demands[row];
    }
  }
  if (j == 0) atomicAdd(&accum[4 + (row0 >> 11)], ddl);
}

// ---------------- sparse row-softmax P ----------------
__global__ void k_prop(const int* __restrict__ adj_idx, const int* __restrict__ adj_cnt,
                       const float* __restrict__ nw, float* __restrict__ Pval) {
  int row = blockIdx.x;
  int lane = threadIdx.x;
  int b = row >> 11;
  int cnt = adj_cnt[row];
  const int* idx = adj_idx + (size_t)row * ADJ_CAP;
  int c0 = (lane < cnt) ? idx[lane] : -1;
  int c1 = (lane + 64 < cnt) ? idx[lane + 64] : -1;
  float v0 = (c0 >= 0) ? nw[b * N_ + c0] : -1e30f;
  float v1 = (c1 >= 0) ? nw[b * N_ + c1] : -1e30f;
  float m = wave_max(fmaxf(v0, v1));
  float e0 = (c0 >= 0) ? __expf(v0 - m) : 0.f;
  float e1 = (c1 >= 0) ? __expf(v1 - m) : 0.f;
  float s = wave_sum(e0 + e1);
  float inv = (s > 0.f) ? 1.f / s : 0.f;
  if (c0 >= 0) Pval[(size_t)row * ADJ_CAP + lane] = e0 * inv;
  if (c1 >= 0) Pval[(size_t)row * ADJ_CAP + lane + 64] = e1 * inv;
}

// ---------------- MCF fixed point: s_{t+1}=relu(P^T s_t - d), one block per batch -----
__global__ void k_mcf(const int* __restrict__ adj_idx, const int* __restrict__ adj_cnt,
                      const float* __restrict__ Pval, const float* __restrict__ demands,
                      float* __restrict__ s_out) {
  int b = blockIdx.x;
  int tid = threadIdx.x;  // 1024
  __shared__ float S[N_], C[N_], D[N_];
  for (int i = tid; i < N_; i += 1024) {
    float d = demands[b * N_ + i];
    D[i] = d;
    S[i] = fmaxf(-d, 0.f);  // s_1 = relu(-d)
  }
  __syncthreads();
  int w = tid >> 6, lane = tid & 63;
  for (int it = 0; it < 9; it++) {
    for (int i = tid; i < N_; i += 1024) C[i] = 0.f;
    __syncthreads();
    for (int i = w; i < N_; i += 16) {
      float si = S[i];
      if (si != 0.f) {
        int cnt = adj_cnt[b * N_ + i];
        const int* idx = adj_idx + ((size_t)b * N_ + i) * ADJ_CAP;
        const float* pv = Pval + ((size_t)b * N_ + i) * ADJ_CAP;
        for (int t = lane; t < cnt; t += 64) atomicAdd(&C[idx[t]], si * pv[t]);
      }
    }
    __syncthreads();
    for (int i = tid; i < N_; i += 1024) S[i] = fmaxf(C[i] - D[i], 0.f);
    __syncthreads();
  }
  for (int i = tid; i < N_; i += 1024) s_out[b * N_ + i] = S[i];
}

// ---------------- flow cost + dual recurrence per adjacency edge ----------------
__global__ void k_flowdual(const int* __restrict__ adj_idx, const int* __restrict__ adj_cnt,
                           const float* __restrict__ Pval, const float* __restrict__ s,
                           const float* __restrict__ dv, float* accum) {
  int tid = threadIdx.x;  // 256
  int lane = tid & 63, w = tid >> 6;
  int row0 = blockIdx.x * 8;
  float fc = 0.f, dc = 0.f;
  for (int rr = w; rr < 8; rr += 4) {
    int row = row0 + rr;
    int b = row >> 11, i = row & (N_ - 1);
    int cnt = adj_cnt[row];
    float si = s[row], dvi = dv[row];
    const int* idx = adj_idx + (size_t)row * ADJ_CAP;
    const float* pv = Pval + (size_t)row * ADJ_CAP;
    for (int t = lane; t < cnt; t += 64) {
      int j = idx[t];
      float f_ij = si * pv[t];
      const int* jidx = adj_idx + (size_t)(b * N_ + j) * ADJ_CAP;
      int jcnt = adj_cnt[b * N_ + j];
      int lo = 0, hi = jcnt, pos = -1;
      while (lo < hi) {
        int mid = (lo + hi) >> 1;
        int v = jidx[mid];
        if (v == i) { pos = mid; break; }
        if (v < i) lo = mid + 1; else hi = mid;
      }
      float f_ji = (pos >= 0) ? s[b * N_ + j] * Pval[(size_t)(b * N_ + j) * ADJ_CAP + pos] : 0.f;
      float fin = f_ij - fminf(f_ij, f_ji);
      fc += fin * fin;
      float dd = dvi - dv[b * N_ + j];
      float y = 0.f, m = 0.f;
      #pragma unroll
      for (int q = 0; q < 10; q++) {
        float g = 2.f * y - dd;
        m = 0.9f * m + g;
        y = fmaxf(y - 0.1f * m, 0.f);
      }
      dc += y * y - dd * y;
    }
  }
  fc = wave_sum(fc); dc = wave_sum(dc);
  __shared__ float FB[4], DB[4];
  if (lane == 0) { FB[w] = fc; DB[w] = dc; }
  __syncthreads();
  if (tid == 0) {
    int b = row0 >> 11;
    atomicAdd(&accum[b], FB[0] + FB[1] + FB[2] + FB[3]);
    atomicAdd(&accum[2 + b], DB[0] + DB[1] + DB[2] + DB[3]);
  }
}

// ---------------- finalize ----------------
__global__ void k_fin(const float* accum, float* out) {
  int b = threadIdx.x;
  if (b < B_) out[b] = accum[b] - accum[2 + b] + accum[4 + b];
}

extern "C" void kernel_launch(void* const* d_in, const int* in_sizes, int n_in,
                              void* d_out, int out_size, void* d_ws, size_t ws_size,
                              hipStream_t stream) {
  const float* feat    = (const float*)d_in[0];
  const float* emb     = (const float*)d_in[1];
  const float* demands = (const float*)d_in[2];
  // d_in[3] (adj) == neighborhoods[0]; not read.
  const float* nbhd    = (const float*)d_in[4];
  const float* enc_W0  = (const float*)d_in[5];
  const float* enc_b0  = (const float*)d_in[6];
  const float* enc_W1  = (const float*)d_in[7];
  const float* enc_b1  = (const float*)d_in[8];
  const float* attn_W  = (const float*)d_in[9];
  const float* a_src   = (const float*)d_in[10];
  const float* a_dst   = (const float*)d_in[11];
  const float* nbr_q   = (const float*)d_in[12];
  const float* gru_W   = (const float*)d_in[13];
  const float* gru_U   = (const float*)d_in[14];
  const float* gru_b   = (const float*)d_in[15];
  const float* dec_W0  = (const float*)d_in[16];
  const float* dec_b0  = (const float*)d_in[17];
  const float* dec_W1  = (const float*)d_in[18];
  const float* dec_b1  = (const float*)d_in[19];
  const float* dual_W0 = (const float*)d_in[20];
  const float* dual_b0 = (const float*)d_in[21];
  const float* dual_W1 = (const float*)d_in[22];
  const float* dual_b1 = (const float*)d_in[23];
  float* out = (float*)d_out;

  char* ws = (char*)d_ws;
  size_t off = 0;
  auto alloc = [&](size_t bytes) { char* p = ws + off; off += (bytes + 255) & ~(size_t)255; return p; };
  int*   adj_idx = (int*)  alloc((size_t)B_ * N_ * ADJ_CAP * 4);
  int*   adj_cnt = (int*)  alloc((size_t)B_ * N_ * 4);
  int*   a2_idx  = (int*)  alloc((size_t)B_ * N_ * A2_CAP * 4);
  int*   a2_cnt  = (int*)  alloc((size_t)B_ * N_ * 4);
  float* h       = (float*)alloc((size_t)B_ * N_ * 64 * 4);
  float* z       = (float*)alloc((size_t)2 * B_ * N_ * 64 * 4);
  float* ssrc    = (float*)alloc((size_t)2 * B_ * N_ * 4);
  float* sdst    = (float*)alloc((size_t)2 * B_ * N_ * 4);
  float* aggs    = (float*)alloc((size_t)B_ * N_ * 2 * 64 * 4);
  float* nw      = (float*)alloc((size_t)B_ * N_ * 4);
  float* dv      = (float*)alloc((size_t)B_ * N_ * 4);
  float* Pval    = (float*)alloc((size_t)B_ * N_ * ADJ_CAP * 4);
  float* s_final = (float*)alloc((size_t)B_ * N_ * 4);
  float* accum   = (float*)alloc(8 * 4);

  k_init<<<1, 64, 0, stream>>>(accum);
  k_csr<<<(2 * B_ * N_) / 4, 256, 0, stream>>>(nbhd, adj_idx, adj_cnt, a2_idx, a2_cnt);
  k_enc<<<(B_ * N_) / ROWS, 64, 0, stream>>>(emb, feat, enc_W0, enc_b0, enc_W1, enc_b1, h);
  for (int layer = 0; layer < 2; layer++) {
    k_z<<<(B_ * N_) / ROWS, 128, 0, stream>>>(h, attn_W, a_src, a_dst, z, ssrc, sdst);
    k_agg<<<B_ * N_ * 2, 64, 0, stream>>>(adj_idx, adj_cnt, a2_idx, a2_cnt, z, ssrc, sdst, aggs);
    k_comb<<<(B_ * N_) / ROWS, 128, 0, stream>>>(aggs, nbr_q, gru_W, gru_U, gru_b, h);
  }
  k_dec<<<(B_ * N_) / ROWS, 64, 0, stream>>>(h, dec_W0, dec_b0, dec_W1, dec_b1,
                                             dual_W0, dual_b0, dual_W1, dual_b1,
                                             demands, nw, dv, accum);
  k_prop<<<B_ * N_, 64, 0, stream>>>(adj_idx, adj_cnt, nw, Pval);
  k_mcf<<<B_, 1024, 0, stream>>>(adj_idx, adj_cnt, Pval, demands, s_final);
  k_flowdual<<<(B_ * N_) / 8, 256, 0, stream>>>(adj_idx, adj_cnt, Pval, s_final, dv, accum);
  k_fin<<<1, 64, 0, stream>>>(accum, out);
}

// Round 2
// 541.027 us; speedup vs baseline: 1.7866x; 1.7866x over previous
//
#include <hip/hip_runtime.h>

#define B_ 2
#define N_ 2048
#define E_ 64
#define FIN_ 18
#define ADJ_CAP 128
#define A2_CAP 1024
#define ROWS 8

__device__ __forceinline__ float wave_sum(float v) {
  #pragma unroll
  for (int o = 32; o > 0; o >>= 1) v += __shfl_xor(v, o);
  return v;
}
__device__ __forceinline__ float wave_max(float v) {
  #pragma unroll
  for (int o = 32; o > 0; o >>= 1) v = fmaxf(v, __shfl_xor(v, o));
  return v;
}

// ---------------- zero accumulators + transpose counters ----------------
__global__ void k_zero(int* __restrict__ tcnt, float* __restrict__ accum) {
  int i = blockIdx.x * 256 + threadIdx.x;
  if (i < B_ * N_) tcnt[i] = 0;
  if (i < 8) accum[i] = 0.f;
}

// ---------------- build CSR from neighborhoods (K=2,B,N,N) ----------------
__global__ void k_csr(const float* __restrict__ nbhd, int* __restrict__ adj_idx,
                      int* __restrict__ adj_cnt, int* __restrict__ a2_idx,
                      int* __restrict__ a2_cnt) {
  int wid = blockIdx.x * 4 + (threadIdx.x >> 6);  // 0 .. 2*B*N-1
  int lane = threadIdx.x & 63;
  int k = wid / (B_ * N_);
  int rem = wid - k * (B_ * N_);  // b*N + i
  const float* row = nbhd + ((size_t)k * (B_ * N_) + rem) * N_;
  int cap = (k == 0) ? ADJ_CAP : A2_CAP;
  int* idx = ((k == 0) ? adj_idx : a2_idx) + (size_t)rem * cap;
  int* cntp = ((k == 0) ? adj_cnt : a2_cnt) + rem;
  int cnt = 0;
  for (int j0 = 0; j0 < N_; j0 += 64) {
    float v = row[j0 + lane];
    bool p = v > 0.f;
    unsigned long long m = __ballot(p);
    int pre = __popcll(m & ((1ull << lane) - 1ull));
    if (p) { int pos = cnt + pre; if (pos < cap) idx[pos] = j0 + lane; }
    cnt += __popcll(m);
  }
  if (lane == 0) *cntp = (cnt < cap) ? cnt : cap;
}

// ---------------- encoder: h = tanh(tanh(x@W0+b0)@W1+b1) ----------------
__global__ void k_enc(const float* __restrict__ emb, const float* __restrict__ feat,
                      const float* __restrict__ W0, const float* __restrict__ b0,
                      const float* __restrict__ W1, const float* __restrict__ b1,
                      float* __restrict__ h) {
  int j = threadIdx.x;  // 64
  int row0 = blockIdx.x * ROWS;
  __shared__ float X[ROWS][FIN_];
  __shared__ float HID[ROWS][64];
  for (int t = j; t < ROWS * FIN_; t += 64) {
    int r = t / FIN_, d = t % FIN_;
    int row = row0 + r;
    X[r][d] = (d < 16) ? emb[(size_t)row * 16 + d] : feat[(size_t)row * 2 + (d - 16)];
  }
  __syncthreads();
  float acc[ROWS];
  #pragma unroll
  for (int r = 0; r < ROWS; r++) acc[r] = b0[j];
  for (int d = 0; d < FIN_; d++) {
    float w = W0[d * 64 + j];
    #pragma unroll
    for (int r = 0; r < ROWS; r++) acc[r] += X[r][d] * w;
  }
  #pragma unroll
  for (int r = 0; r < ROWS; r++) HID[r][j] = tanhf(acc[r]);
  __syncthreads();
  float acc2[ROWS];
  #pragma unroll
  for (int r = 0; r < ROWS; r++) acc2[r] = b1[j];
  for (int d = 0; d < 64; d++) {
    float w = W1[d * 64 + j];
    #pragma unroll
    for (int r = 0; r < ROWS; r++) acc2[r] += HID[r][d] * w;
  }
  #pragma unroll
  for (int r = 0; r < ROWS; r++) h[(size_t)(row0 + r) * 64 + j] = tanhf(acc2[r]);
}

// ---------------- z = h@attn_W[head], s_src, s_dst ----------------
__global__ void k_z(const float* __restrict__ h, const float* __restrict__ attn_W,
                    const float* __restrict__ a_src, const float* __restrict__ a_dst,
                    float* __restrict__ z, float* __restrict__ ssrc, float* __restrict__ sdst) {
  int tid = threadIdx.x;  // 128
  int head = tid >> 6, j = tid & 63;
  int row0 = blockIdx.x * ROWS;
  __shared__ float HR[ROWS][64];
  for (int t = tid; t < ROWS * 64; t += 128) HR[t >> 6][t & 63] = h[(size_t)row0 * 64 + t];
  __syncthreads();
  float acc[ROWS];
  #pragma unroll
  for (int r = 0; r < ROWS; r++) acc[r] = 0.f;
  const float* W = attn_W + head * 64 * 64;
  for (int d = 0; d < 64; d++) {
    float w = W[d * 64 + j];
    #pragma unroll
    for (int r = 0; r < ROWS; r++) acc[r] += HR[r][d] * w;
  }
  float as = a_src[head * 64 + j], ad = a_dst[head * 64 + j];
  #pragma unroll
  for (int r = 0; r < ROWS; r++) {
    float zv = acc[r];
    z[((size_t)head * (B_ * N_) + row0 + r) * 64 + j] = zv;
    float rs = wave_sum(zv * as);
    float rd = wave_sum(zv * ad);
    if (j == 0) {
      ssrc[head * (B_ * N_) + row0 + r] = rs;
      sdst[head * (B_ * N_) + row0 + r] = rd;
    }
  }
}

// ---------------- sparse masked-softmax attention aggregate ----------------
__global__ void k_agg(const int* __restrict__ adj_idx, const int* __restrict__ adj_cnt,
                      const int* __restrict__ a2_idx, const int* __restrict__ a2_cnt,
                      const float* __restrict__ z, const float* __restrict__ ssrc,
                      const float* __restrict__ sdst, float* __restrict__ aggs) {
  int k = blockIdx.x & 1;
  int row = blockIdx.x >> 1;  // b*N+i
  int lane = threadIdx.x;     // 64
  int b = row >> 11;
  int cap = (k == 0) ? ADJ_CAP : A2_CAP;
  const int* idx = ((k == 0) ? adj_idx : a2_idx) + (size_t)row * cap;
  int cnt = ((k == 0) ? adj_cnt : a2_cnt)[row];
  __shared__ float SC0[A2_CAP], SC1[A2_CAP];
  __shared__ int COL[A2_CAP];
  float ss0 = ssrc[row], ss1 = ssrc[B_ * N_ + row];
  const float* sd0 = sdst + b * N_;
  const float* sd1 = sdst + B_ * N_ + b * N_;
  float m0 = -1e30f, m1 = -1e30f;
  for (int t = lane; t < cnt; t += 64) {
    int c = idx[t];
    COL[t] = c;
    float s0 = tanhf(ss0 + sd0[c]);
    float s1 = tanhf(ss1 + sd1[c]);
    SC0[t] = s0; SC1[t] = s1;
    m0 = fmaxf(m0, s0); m1 = fmaxf(m1, s1);
  }
  m0 = wave_max(m0); m1 = wave_max(m1);
  float sum0 = 0.f, sum1 = 0.f;
  for (int t = lane; t < cnt; t += 64) {  // same lanes as wrote -> no sync needed yet
    float e0 = __expf(SC0[t] - m0);
    float e1 = __expf(SC1[t] - m1);
    SC0[t] = e0; SC1[t] = e1;
    sum0 += e0; sum1 += e1;
  }
  sum0 = wave_sum(sum0); sum1 = wave_sum(sum1);
  float inv0 = (sum0 > 0.f) ? 1.f / sum0 : 0.f;
  float inv1 = (sum1 > 0.f) ? 1.f / sum1 : 0.f;
  __syncthreads();
  const float* z0 = z + ((size_t)b * N_) * 64;
  const float* z1 = z + ((size_t)(B_ * N_) + b * N_) * 64;
  float acc0 = 0.f, acc1 = 0.f;
  #pragma unroll 4
  for (int t = 0; t < cnt; t++) {
    int c = COL[t];
    float a0 = SC0[t] * inv0, a1 = SC1[t] * inv1;
    acc0 += a0 * z0[(size_t)c * 64 + lane];
    acc1 += a1 * z1[(size_t)c * 64 + lane];
  }
  aggs[((size_t)row * 2 + k) * 64 + lane] = tanhf(0.5f * (acc0 + acc1));
}

// ---------------- nbr-softmax combine + GRU ----------------
__global__ void k_comb(const float* __restrict__ aggs, const float* __restrict__ nbr_q,
                       const float* __restrict__ gru_W, const float* __restrict__ gru_U,
                       const float* __restrict__ gru_b, float* __restrict__ h) {
  int tid = threadIdx.x;  // 128
  int w = tid >> 6, j = tid & 63;
  int row0 = blockIdx.x * ROWS;
  __shared__ float NXT[ROWS][64], HROW[ROWS][64], RG[ROWS][64], ZG[ROWS][64];
  for (int t = tid; t < ROWS * 64; t += 128) HROW[t >> 6][t & 63] = h[(size_t)row0 * 64 + t];
  float q = nbr_q[j];
  for (int r = w * (ROWS / 2); r < (w + 1) * (ROWS / 2); r++) {
    float a0 = aggs[((size_t)(row0 + r) * 2 + 0) * 64 + j];
    float a1 = aggs[((size_t)(row0 + r) * 2 + 1) * 64 + j];
    float t0 = tanhf(wave_sum(a0 * q));
    float t1 = tanhf(wave_sum(a1 * q));
    float mx = fmaxf(t0, t1);
    float e0 = __expf(t0 - mx), e1 = __expf(t1 - mx);
    float inv = 1.f / (e0 + e1);
    NXT[r][j] = (e0 * a0 + e1 * a1) * inv;
  }
  __syncthreads();
  {
    float acc[ROWS];
    #pragma unroll
    for (int r = 0; r < ROWS; r++) acc[r] = gru_b[tid];
    for (int d = 0; d < 64; d++) {
      float wW = gru_W[d * 192 + tid];
      float wU = gru_U[d * 192 + tid];
      #pragma unroll
      for (int r = 0; r < ROWS; r++) acc[r] += NXT[r][d] * wW + HROW[r][d] * wU;
    }
    #pragma unroll
    for (int r = 0; r < ROWS; r++) {
      float zr = 1.f / (1.f + __expf(-acc[r]));
      if (tid < 64) ZG[r][tid] = zr; else RG[r][tid - 64] = zr;
    }
  }
  __syncthreads();
  if (tid < 64) {
    int col = 128 + tid;
    float acc[ROWS];
    #pragma unroll
    for (int r = 0; r < ROWS; r++) acc[r] = gru_b[col];
    for (int d = 0; d < 64; d++) {
      float wW = gru_W[d * 192 + col];
      float wU = gru_U[d * 192 + col];
      #pragma unroll
      for (int r = 0; r < ROWS; r++) acc[r] += NXT[r][d] * wW + (RG[r][d] * HROW[r][d]) * wU;
    }
    #pragma unroll
    for (int r = 0; r < ROWS; r++) {
      float ht = tanhf(acc[r]);
      float zg = ZG[r][tid];
      h[(size_t)(row0 + r) * 64 + tid] = (1.f - zg) * HROW[r][tid] + zg * ht;
    }
  }
}

// ---------------- decoder + dual heads (+ dual_demand) ----------------
__global__ void k_dec(const float* __restrict__ h, const float* __restrict__ dW0,
                      const float* __restrict__ db0, const float* __restrict__ dW1,
                      const float* __restrict__ db1, const float* __restrict__ uW0,
                      const float* __restrict__ ub0, const float* __restrict__ uW1,
                      const float* __restrict__ ub1, const float* __restrict__ demands,
                      float* __restrict__ nw, float* __restrict__ dv, float* accum) {
  int j = threadIdx.x;  // 64
  int row0 = blockIdx.x * ROWS;
  __shared__ float HROW[ROWS][64];
  for (int t = j; t < ROWS * 64; t += 64) HROW[t >> 6][t & 63] = h[(size_t)row0 * 64 + t];
  __syncthreads();
  float hd[ROWS], hu[ROWS];
  #pragma unroll
  for (int r = 0; r < ROWS; r++) { hd[r] = db0[j]; hu[r] = ub0[j]; }
  for (int d = 0; d < 64; d++) {
    float w0 = dW0[d * 64 + j], u0 = uW0[d * 64 + j];
    #pragma unroll
    for (int r = 0; r < ROWS; r++) { hd[r] += HROW[r][d] * w0; hu[r] += HROW[r][d] * u0; }
  }
  float w1 = dW1[j], u1 = uW1[j];
  float ddl = 0.f;
  #pragma unroll
  for (int r = 0; r < ROWS; r++) {
    float a = wave_sum(tanhf(hd[r]) * w1);
    float bb = wave_sum(tanhf(hu[r]) * u1);
    if (j == 0) {
      int row = row0 + r;
      float nwv = a + db1[0], dvv = bb + ub1[0];
      nw[row] = nwv; dv[row] = dvv;
      ddl += dvv * demands[row];
    }
  }
  if (j == 0) atomicAdd(&accum[4 + (row0 >> 11)], ddl);
}

// ---------------- sparse row-softmax P (+ s_1 = relu(-d) init) ----------------
__global__ void k_prop(const int* __restrict__ adj_idx, const int* __restrict__ adj_cnt,
                       const float* __restrict__ nw, const float* __restrict__ demands,
                       float* __restrict__ Pval, float* __restrict__ sA) {
  int row = blockIdx.x;
  int lane = threadIdx.x;
  int b = row >> 11;
  int cnt = adj_cnt[row];
  const int* idx = adj_idx + (size_t)row * ADJ_CAP;
  int c0 = (lane < cnt) ? idx[lane] : -1;
  int c1 = (lane + 64 < cnt) ? idx[lane + 64] : -1;
  float v0 = (c0 >= 0) ? nw[b * N_ + c0] : -1e30f;
  float v1 = (c1 >= 0) ? nw[b * N_ + c1] : -1e30f;
  float m = wave_max(fmaxf(v0, v1));
  float e0 = (c0 >= 0) ? __expf(v0 - m) : 0.f;
  float e1 = (c1 >= 0) ? __expf(v1 - m) : 0.f;
  float s = wave_sum(e0 + e1);
  float inv = (s > 0.f) ? 1.f / s : 0.f;
  if (c0 >= 0) Pval[(size_t)row * ADJ_CAP + lane] = e0 * inv;
  if (c1 >= 0) Pval[(size_t)row * ADJ_CAP + lane + 64] = e1 * inv;
  if (lane == 0) sA[row] = fmaxf(-demands[row], 0.f);
}

// ---------------- transposed CSR of (adj, Pval): in-edges per column ----------------
__global__ void k_transpose(const int* __restrict__ adj_idx, const int* __restrict__ adj_cnt,
                            const float* __restrict__ Pval, int* __restrict__ tcnt,
                            int* __restrict__ tsrc, float* __restrict__ tval) {
  int row = blockIdx.x;  // b*N+i
  int lane = threadIdx.x;
  int cnt = adj_cnt[row];
  int base = row & ~(N_ - 1);  // b*N
  for (int t = lane; t < cnt; t += 64) {
    int j = adj_idx[(size_t)row * ADJ_CAP + t];
    int col = base + j;
    int pos = atomicAdd(&tcnt[col], 1);
    if (pos < ADJ_CAP) {
      tsrc[(size_t)col * ADJ_CAP + pos] = row;  // global source row
      tval[(size_t)col * ADJ_CAP + pos] = Pval[(size_t)row * ADJ_CAP + t];
    }
  }
}

// ---------------- one MCF iteration: s_out[j] = relu(sum_i P[i][j] s_in[i] - d[j]) ----
__global__ void k_mcf_iter(const int* __restrict__ tcnt, const int* __restrict__ tsrc,
                           const float* __restrict__ tval, const float* __restrict__ demands,
                           const float* __restrict__ s_in, float* __restrict__ s_out) {
  int j = blockIdx.x * 64 + threadIdx.x;  // 0..B*N-1
  int cnt = tcnt[j];
  const int* src = tsrc + (size_t)j * ADJ_CAP;
  const float* val = tval + (size_t)j * ADJ_CAP;
  float c = 0.f;
  #pragma unroll 4
  for (int t = 0; t < cnt; t++) c += val[t] * s_in[src[t]];
  s_out[j] = fmaxf(c - demands[j], 0.f);
}

// ---------------- flow cost + dual recurrence per adjacency edge ----------------
__global__ void k_flowdual(const int* __restrict__ adj_idx, const int* __restrict__ adj_cnt,
                           const float* __restrict__ Pval, const float* __restrict__ s,
                           const float* __restrict__ dv, float* accum) {
  int tid = threadIdx.x;  // 256
  int lane = tid & 63, w = tid >> 6;
  int row0 = blockIdx.x * 8;
  float fc = 0.f, dc = 0.f;
  for (int rr = w; rr < 8; rr += 4) {
    int row = row0 + rr;
    int b = row >> 11, i = row & (N_ - 1);
    int cnt = adj_cnt[row];
    float si = s[row], dvi = dv[row];
    const int* idx = adj_idx + (size_t)row * ADJ_CAP;
    const float* pv = Pval + (size_t)row * ADJ_CAP;
    for (int t = lane; t < cnt; t += 64) {
      int j = idx[t];
      float f_ij = si * pv[t];
      const int* jidx = adj_idx + (size_t)(b * N_ + j) * ADJ_CAP;
      int jcnt = adj_cnt[b * N_ + j];
      int lo = 0, hi = jcnt, pos = -1;
      while (lo < hi) {
        int mid = (lo + hi) >> 1;
        int v = jidx[mid];
        if (v == i) { pos = mid; break; }
        if (v < i) lo = mid + 1; else hi = mid;
      }
      float f_ji = (pos >= 0) ? s[b * N_ + j] * Pval[(size_t)(b * N_ + j) * ADJ_CAP + pos] : 0.f;
      float fin = f_ij - fminf(f_ij, f_ji);
      fc += fin * fin;
      float dd = dvi - dv[b * N_ + j];
      float y = 0.f, m = 0.f;
      #pragma unroll
      for (int q = 0; q < 10; q++) {
        float g = 2.f * y - dd;
        m = 0.9f * m + g;
        y = fmaxf(y - 0.1f * m, 0.f);
      }
      dc += y * y - dd * y;
    }
  }
  fc = wave_sum(fc); dc = wave_sum(dc);
  __shared__ float FB[4], DB[4];
  if (lane == 0) { FB[w] = fc; DB[w] = dc; }
  __syncthreads();
  if (tid == 0) {
    int b = row0 >> 11;
    atomicAdd(&accum[b], FB[0] + FB[1] + FB[2] + FB[3]);
    atomicAdd(&accum[2 + b], DB[0] + DB[1] + DB[2] + DB[3]);
  }
}

// ---------------- finalize ----------------
__global__ void k_fin(const float* accum, float* out) {
  int b = threadIdx.x;
  if (b < B_) out[b] = accum[b] - accum[2 + b] + accum[4 + b];
}

extern "C" void kernel_launch(void* const* d_in, const int* in_sizes, int n_in,
                              void* d_out, int out_size, void* d_ws, size_t ws_size,
                              hipStream_t stream) {
  const float* feat    = (const float*)d_in[0];
  const float* emb     = (const float*)d_in[1];
  const float* demands = (const float*)d_in[2];
  // d_in[3] (adj) == neighborhoods[0]; not read.
  const float* nbhd    = (const float*)d_in[4];
  const float* enc_W0  = (const float*)d_in[5];
  const float* enc_b0  = (const float*)d_in[6];
  const float* enc_W1  = (const float*)d_in[7];
  const float* enc_b1  = (const float*)d_in[8];
  const float* attn_W  = (const float*)d_in[9];
  const float* a_src   = (const float*)d_in[10];
  const float* a_dst   = (const float*)d_in[11];
  const float* nbr_q   = (const float*)d_in[12];
  const float* gru_W   = (const float*)d_in[13];
  const float* gru_U   = (const float*)d_in[14];
  const float* gru_b   = (const float*)d_in[15];
  const float* dec_W0  = (const float*)d_in[16];
  const float* dec_b0  = (const float*)d_in[17];
  const float* dec_W1  = (const float*)d_in[18];
  const float* dec_b1  = (const float*)d_in[19];
  const float* dual_W0 = (const float*)d_in[20];
  const float* dual_b0 = (const float*)d_in[21];
  const float* dual_W1 = (const float*)d_in[22];
  const float* dual_b1 = (const float*)d_in[23];
  float* out = (float*)d_out;

  char* ws = (char*)d_ws;
  size_t off = 0;
  auto alloc = [&](size_t bytes) { char* p = ws + off; off += (bytes + 255) & ~(size_t)255; return p; };
  int*   adj_idx = (int*)  alloc((size_t)B_ * N_ * ADJ_CAP * 4);
  int*   adj_cnt = (int*)  alloc((size_t)B_ * N_ * 4);
  int*   a2_idx  = (int*)  alloc((size_t)B_ * N_ * A2_CAP * 4);
  int*   a2_cnt  = (int*)  alloc((size_t)B_ * N_ * 4);
  float* h       = (float*)alloc((size_t)B_ * N_ * 64 * 4);
  float* z       = (float*)alloc((size_t)2 * B_ * N_ * 64 * 4);
  float* ssrc    = (float*)alloc((size_t)2 * B_ * N_ * 4);
  float* sdst    = (float*)alloc((size_t)2 * B_ * N_ * 4);
  float* aggs    = (float*)alloc((size_t)B_ * N_ * 2 * 64 * 4);
  float* nw      = (float*)alloc((size_t)B_ * N_ * 4);
  float* dv      = (float*)alloc((size_t)B_ * N_ * 4);
  float* Pval    = (float*)alloc((size_t)B_ * N_ * ADJ_CAP * 4);
  int*   tcnt    = (int*)  alloc((size_t)B_ * N_ * 4);
  int*   tsrc    = (int*)  alloc((size_t)B_ * N_ * ADJ_CAP * 4);
  float* tval    = (float*)alloc((size_t)B_ * N_ * ADJ_CAP * 4);
  float* sA      = (float*)alloc((size_t)B_ * N_ * 4);
  float* sB      = (float*)alloc((size_t)B_ * N_ * 4);
  float* accum   = (float*)alloc(8 * 4);

  k_zero<<<(B_ * N_ + 255) / 256, 256, 0, stream>>>(tcnt, accum);
  k_csr<<<(2 * B_ * N_) / 4, 256, 0, stream>>>(nbhd, adj_idx, adj_cnt, a2_idx, a2_cnt);
  k_enc<<<(B_ * N_) / ROWS, 64, 0, stream>>>(emb, feat, enc_W0, enc_b0, enc_W1, enc_b1, h);
  for (int layer = 0; layer < 2; layer++) {
    k_z<<<(B_ * N_) / ROWS, 128, 0, stream>>>(h, attn_W, a_src, a_dst, z, ssrc, sdst);
    k_agg<<<B_ * N_ * 2, 64, 0, stream>>>(adj_idx, adj_cnt, a2_idx, a2_cnt, z, ssrc, sdst, aggs);
    k_comb<<<(B_ * N_) / ROWS, 128, 0, stream>>>(aggs, nbr_q, gru_W, gru_U, gru_b, h);
  }
  k_dec<<<(B_ * N_) / ROWS, 64, 0, stream>>>(h, dec_W0, dec_b0, dec_W1, dec_b1,
                                             dual_W0, dual_b0, dual_W1, dual_b1,
                                             demands, nw, dv, accum);
  k_prop<<<B_ * N_, 64, 0, stream>>>(adj_idx, adj_cnt, nw, demands, Pval, sA);
  k_transpose<<<B_ * N_, 64, 0, stream>>>(adj_idx, adj_cnt, Pval, tcnt, tsrc, tval);
  // s_1 = relu(-d) in sA; 9 more iterations -> s_10 ends in sB
  for (int it = 0; it < 9; it++) {
    float* sin  = (it & 1) ? sB : sA;
    float* sout = (it & 1) ? sA : sB;
    k_mcf_iter<<<(B_ * N_) / 64, 64, 0, stream>>>(tcnt, tsrc, tval, demands, sin, sout);
  }
  k_flowdual<<<(B_ * N_) / 8, 256, 0, stream>>>(adj_idx, adj_cnt, Pval, sB, dv, accum);
  k_fin<<<1, 64, 0, stream>>>(accum, out);
}

// Round 3
// 454.428 us; speedup vs baseline: 2.1270x; 1.1906x over previous
//
#include <hip/hip_runtime.h>

#define B_ 2
#define N_ 2048
#define E_ 64
#define FIN_ 18
#define ADJ_CAP 128
#define A2_CAP 1024
#define ROWS 8

__device__ __forceinline__ float wave_sum(float v) {
  #pragma unroll
  for (int o = 32; o > 0; o >>= 1) v += __shfl_xor(v, o);
  return v;
}
__device__ __forceinline__ float wave_max(float v) {
  #pragma unroll
  for (int o = 32; o > 0; o >>= 1) v = fmaxf(v, __shfl_xor(v, o));
  return v;
}

// ---------------- zero accumulators + transpose counters ----------------
__global__ void k_zero(int* __restrict__ tcnt, float* __restrict__ accum) {
  int i = blockIdx.x * 256 + threadIdx.x;
  if (i < B_ * N_) tcnt[i] = 0;
  if (i < 8) accum[i] = 0.f;
}

// ---------------- build CSR from neighborhoods (K=2,B,N,N) ----------------
__global__ void k_csr(const float* __restrict__ nbhd, int* __restrict__ adj_idx,
                      int* __restrict__ adj_cnt, int* __restrict__ a2_idx,
                      int* __restrict__ a2_cnt) {
  int wid = blockIdx.x * 4 + (threadIdx.x >> 6);  // 0 .. 2*B*N-1
  int lane = threadIdx.x & 63;
  int k = wid / (B_ * N_);
  int rem = wid - k * (B_ * N_);  // b*N + i
  const float* row = nbhd + ((size_t)k * (B_ * N_) + rem) * N_;
  int cap = (k == 0) ? ADJ_CAP : A2_CAP;
  int* idx = ((k == 0) ? adj_idx : a2_idx) + (size_t)rem * cap;
  int* cntp = ((k == 0) ? adj_cnt : a2_cnt) + rem;
  int cnt = 0;
  for (int j0 = 0; j0 < N_; j0 += 64) {
    float v = row[j0 + lane];
    bool p = v > 0.f;
    unsigned long long m = __ballot(p);
    int pre = __popcll(m & ((1ull << lane) - 1ull));
    if (p) { int pos = cnt + pre; if (pos < cap) idx[pos] = j0 + lane; }
    cnt += __popcll(m);
  }
  if (lane == 0) *cntp = (cnt < cap) ? cnt : cap;
}

// ---------------- encoder: h = tanh(tanh(x@W0+b0)@W1+b1) ----------------
__global__ void k_enc(const float* __restrict__ emb, const float* __restrict__ feat,
                      const float* __restrict__ W0, const float* __restrict__ b0,
                      const float* __restrict__ W1, const float* __restrict__ b1,
                      float* __restrict__ h) {
  int j = threadIdx.x;  // 64
  int row0 = blockIdx.x * ROWS;
  __shared__ float X[ROWS][FIN_];
  __shared__ float HID[ROWS][64];
  for (int t = j; t < ROWS * FIN_; t += 64) {
    int r = t / FIN_, d = t % FIN_;
    int row = row0 + r;
    X[r][d] = (d < 16) ? emb[(size_t)row * 16 + d] : feat[(size_t)row * 2 + (d - 16)];
  }
  __syncthreads();
  float acc[ROWS];
  #pragma unroll
  for (int r = 0; r < ROWS; r++) acc[r] = b0[j];
  for (int d = 0; d < FIN_; d++) {
    float w = W0[d * 64 + j];
    #pragma unroll
    for (int r = 0; r < ROWS; r++) acc[r] += X[r][d] * w;
  }
  #pragma unroll
  for (int r = 0; r < ROWS; r++) HID[r][j] = tanhf(acc[r]);
  __syncthreads();
  float acc2[ROWS];
  #pragma unroll
  for (int r = 0; r < ROWS; r++) acc2[r] = b1[j];
  for (int d = 0; d < 64; d++) {
    float w = W1[d * 64 + j];
    #pragma unroll
    for (int r = 0; r < ROWS; r++) acc2[r] += HID[r][d] * w;
  }
  #pragma unroll
  for (int r = 0; r < ROWS; r++) h[(size_t)(row0 + r) * 64 + j] = tanhf(acc2[r]);
}

// ---------------- z = h@attn_W[head], s_src, s_dst ----------------
__global__ void k_z(const float* __restrict__ h, const float* __restrict__ attn_W,
                    const float* __restrict__ a_src, const float* __restrict__ a_dst,
                    float* __restrict__ z, float* __restrict__ ssrc, float* __restrict__ sdst) {
  int tid = threadIdx.x;  // 128
  int head = tid >> 6, j = tid & 63;
  int row0 = blockIdx.x * ROWS;
  __shared__ float HR[ROWS][64];
  for (int t = tid; t < ROWS * 64; t += 128) HR[t >> 6][t & 63] = h[(size_t)row0 * 64 + t];
  __syncthreads();
  float acc[ROWS];
  #pragma unroll
  for (int r = 0; r < ROWS; r++) acc[r] = 0.f;
  const float* W = attn_W + head * 64 * 64;
  for (int d = 0; d < 64; d++) {
    float w = W[d * 64 + j];
    #pragma unroll
    for (int r = 0; r < ROWS; r++) acc[r] += HR[r][d] * w;
  }
  float as = a_src[head * 64 + j], ad = a_dst[head * 64 + j];
  #pragma unroll
  for (int r = 0; r < ROWS; r++) {
    float zv = acc[r];
    z[((size_t)head * (B_ * N_) + row0 + r) * 64 + j] = zv;
    float rs = wave_sum(zv * as);
    float rd = wave_sum(zv * ad);
    if (j == 0) {
      ssrc[head * (B_ * N_) + row0 + r] = rs;
      sdst[head * (B_ * N_) + row0 + r] = rd;
    }
  }
}

// ---------------- sparse masked-softmax attention aggregate ----------------
// 256 threads (4 waves). Softmax without max-shift (scores tanh-bounded).
// Phase 2: lane group g=lane>>4 takes neighbor t=base+g, lane loads float4
// chunk (lane&15) of that neighbor's 64-float z row. Cross-group reduce via
// shfl_xor(16/32), cross-wave reduce via LDS.
__global__ void k_agg(const int* __restrict__ adj_idx, const int* __restrict__ adj_cnt,
                      const int* __restrict__ a2_idx, const int* __restrict__ a2_cnt,
                      const float* __restrict__ z, const float* __restrict__ ssrc,
                      const float* __restrict__ sdst, float* __restrict__ aggs) {
  int k = blockIdx.x & 1;
  int row = blockIdx.x >> 1;  // b*N+i
  int tid = threadIdx.x;      // 256
  int w = tid >> 6, lane = tid & 63;
  int b = row >> 11;
  int cap = (k == 0) ? ADJ_CAP : A2_CAP;
  const int* idx = ((k == 0) ? adj_idx : a2_idx) + (size_t)row * cap;
  int cnt = ((k == 0) ? adj_cnt : a2_cnt)[row];
  __shared__ float SC0[A2_CAP], SC1[A2_CAP];
  __shared__ int COL[A2_CAP];
  __shared__ float WS[4][64];
  __shared__ float RED[2][4];
  float ss0 = ssrc[row], ss1 = ssrc[B_ * N_ + row];
  const float* sd0 = sdst + b * N_;
  const float* sd1 = sdst + B_ * N_ + b * N_;
  float sum0 = 0.f, sum1 = 0.f;
  for (int t = tid; t < cnt; t += 256) {
    int c = idx[t];
    COL[t] = c;
    float e0 = __expf(tanhf(ss0 + sd0[c]));
    float e1 = __expf(tanhf(ss1 + sd1[c]));
    SC0[t] = e0; SC1[t] = e1;
    sum0 += e0; sum1 += e1;
  }
  sum0 = wave_sum(sum0); sum1 = wave_sum(sum1);
  if (lane == 0) { RED[0][w] = sum0; RED[1][w] = sum1; }
  __syncthreads();
  float tot0 = RED[0][0] + RED[0][1] + RED[0][2] + RED[0][3];
  float tot1 = RED[1][0] + RED[1][1] + RED[1][2] + RED[1][3];
  float inv0 = (tot0 > 0.f) ? 1.f / tot0 : 0.f;
  float inv1 = (tot1 > 0.f) ? 1.f / tot1 : 0.f;
  const float* z0 = z + ((size_t)b * N_) * 64;
  const float* z1 = z + ((size_t)(B_ * N_) + b * N_) * 64;
  int g = lane >> 4, li = lane & 15;
  float4 a0 = {0.f, 0.f, 0.f, 0.f}, a1 = {0.f, 0.f, 0.f, 0.f};
  for (int base = w * 4; base < cnt; base += 16) {
    int t = base + g;
    if (t < cnt) {
      int c = COL[t];
      float e0 = SC0[t], e1 = SC1[t];
      float4 v0 = ((const float4*)(z0 + (size_t)c * 64))[li];
      float4 v1 = ((const float4*)(z1 + (size_t)c * 64))[li];
      a0.x += e0 * v0.x; a0.y += e0 * v0.y; a0.z += e0 * v0.z; a0.w += e0 * v0.w;
      a1.x += e1 * v1.x; a1.y += e1 * v1.y; a1.z += e1 * v1.z; a1.w += e1 * v1.w;
    }
  }
  // reduce over lane groups (bits 4,5)
  #pragma unroll
  for (int o = 16; o <= 32; o <<= 1) {
    a0.x += __shfl_xor(a0.x, o); a0.y += __shfl_xor(a0.y, o);
    a0.z += __shfl_xor(a0.z, o); a0.w += __shfl_xor(a0.w, o);
    a1.x += __shfl_xor(a1.x, o); a1.y += __shfl_xor(a1.y, o);
    a1.z += __shfl_xor(a1.z, o); a1.w += __shfl_xor(a1.w, o);
  }
  if (g == 0) {
    WS[w][li * 4 + 0] = a0.x * inv0 + a1.x * inv1;
    WS[w][li * 4 + 1] = a0.y * inv0 + a1.y * inv1;
    WS[w][li * 4 + 2] = a0.z * inv0 + a1.z * inv1;
    WS[w][li * 4 + 3] = a0.w * inv0 + a1.w * inv1;
  }
  __syncthreads();
  if (tid < 64) {
    float s = WS[0][tid] + WS[1][tid] + WS[2][tid] + WS[3][tid];
    aggs[((size_t)row * 2 + k) * 64 + tid] = tanhf(0.5f * s);
  }
}

// ---------------- nbr-softmax combine + GRU ----------------
__global__ void k_comb(const float* __restrict__ aggs, const float* __restrict__ nbr_q,
                       const float* __restrict__ gru_W, const float* __restrict__ gru_U,
                       const float* __restrict__ gru_b, float* __restrict__ h) {
  int tid = threadIdx.x;  // 128
  int w = tid >> 6, j = tid & 63;
  int row0 = blockIdx.x * ROWS;
  __shared__ float NXT[ROWS][64], HROW[ROWS][64], RG[ROWS][64], ZG[ROWS][64];
  for (int t = tid; t < ROWS * 64; t += 128) HROW[t >> 6][t & 63] = h[(size_t)row0 * 64 + t];
  float q = nbr_q[j];
  for (int r = w * (ROWS / 2); r < (w + 1) * (ROWS / 2); r++) {
    float a0 = aggs[((size_t)(row0 + r) * 2 + 0) * 64 + j];
    float a1 = aggs[((size_t)(row0 + r) * 2 + 1) * 64 + j];
    float t0 = tanhf(wave_sum(a0 * q));
    float t1 = tanhf(wave_sum(a1 * q));
    float mx = fmaxf(t0, t1);
    float e0 = __expf(t0 - mx), e1 = __expf(t1 - mx);
    float inv = 1.f / (e0 + e1);
    NXT[r][j] = (e0 * a0 + e1 * a1) * inv;
  }
  __syncthreads();
  {
    float acc[ROWS];
    #pragma unroll
    for (int r = 0; r < ROWS; r++) acc[r] = gru_b[tid];
    for (int d = 0; d < 64; d++) {
      float wW = gru_W[d * 192 + tid];
      float wU = gru_U[d * 192 + tid];
      #pragma unroll
      for (int r = 0; r < ROWS; r++) acc[r] += NXT[r][d] * wW + HROW[r][d] * wU;
    }
    #pragma unroll
    for (int r = 0; r < ROWS; r++) {
      float zr = 1.f / (1.f + __expf(-acc[r]));
      if (tid < 64) ZG[r][tid] = zr; else RG[r][tid - 64] = zr;
    }
  }
  __syncthreads();
  if (tid < 64) {
    int col = 128 + tid;
    float acc[ROWS];
    #pragma unroll
    for (int r = 0; r < ROWS; r++) acc[r] = gru_b[col];
    for (int d = 0; d < 64; d++) {
      float wW = gru_W[d * 192 + col];
      float wU = gru_U[d * 192 + col];
      #pragma unroll
      for (int r = 0; r < ROWS; r++) acc[r] += NXT[r][d] * wW + (RG[r][d] * HROW[r][d]) * wU;
    }
    #pragma unroll
    for (int r = 0; r < ROWS; r++) {
      float ht = tanhf(acc[r]);
      float zg = ZG[r][tid];
      h[(size_t)(row0 + r) * 64 + tid] = (1.f - zg) * HROW[r][tid] + zg * ht;
    }
  }
}

// ---------------- decoder + dual heads (+ dual_demand) ----------------
__global__ void k_dec(const float* __restrict__ h, const float* __restrict__ dW0,
                      const float* __restrict__ db0, const float* __restrict__ dW1,
                      const float* __restrict__ db1, const float* __restrict__ uW0,
                      const float* __restrict__ ub0, const float* __restrict__ uW1,
                      const float* __restrict__ ub1, const float* __restrict__ demands,
                      float* __restrict__ nw, float* __restrict__ dv, float* accum) {
  int j = threadIdx.x;  // 64
  int row0 = blockIdx.x * ROWS;
  __shared__ float HROW[ROWS][64];
  for (int t = j; t < ROWS * 64; t += 64) HROW[t >> 6][t & 63] = h[(size_t)row0 * 64 + t];
  __syncthreads();
  float hd[ROWS], hu[ROWS];
  #pragma unroll
  for (int r = 0; r < ROWS; r++) { hd[r] = db0[j]; hu[r] = ub0[j]; }
  for (int d = 0; d < 64; d++) {
    float w0 = dW0[d * 64 + j], u0 = uW0[d * 64 + j];
    #pragma unroll
    for (int r = 0; r < ROWS; r++) { hd[r] += HROW[r][d] * w0; hu[r] += HROW[r][d] * u0; }
  }
  float w1 = dW1[j], u1 = uW1[j];
  float ddl = 0.f;
  #pragma unroll
  for (int r = 0; r < ROWS; r++) {
    float a = wave_sum(tanhf(hd[r]) * w1);
    float bb = wave_sum(tanhf(hu[r]) * u1);
    if (j == 0) {
      int row = row0 + r;
      float nwv = a + db1[0], dvv = bb + ub1[0];
      nw[row] = nwv; dv[row] = dvv;
      ddl += dvv * demands[row];
    }
  }
  if (j == 0) atomicAdd(&accum[4 + (row0 >> 11)], ddl);
}

// ---------------- sparse row-softmax P (+ s_1 = relu(-d) init) ----------------
__global__ void k_prop(const int* __restrict__ adj_idx, const int* __restrict__ adj_cnt,
                       const float* __restrict__ nw, const float* __restrict__ demands,
                       float* __restrict__ Pval, float* __restrict__ sA) {
  int row = blockIdx.x;
  int lane = threadIdx.x;
  int b = row >> 11;
  int cnt = adj_cnt[row];
  const int* idx = adj_idx + (size_t)row * ADJ_CAP;
  int c0 = (lane < cnt) ? idx[lane] : -1;
  int c1 = (lane + 64 < cnt) ? idx[lane + 64] : -1;
  float v0 = (c0 >= 0) ? nw[b * N_ + c0] : -1e30f;
  float v1 = (c1 >= 0) ? nw[b * N_ + c1] : -1e30f;
  float m = wave_max(fmaxf(v0, v1));
  float e0 = (c0 >= 0) ? __expf(v0 - m) : 0.f;
  float e1 = (c1 >= 0) ? __expf(v1 - m) : 0.f;
  float s = wave_sum(e0 + e1);
  float inv = (s > 0.f) ? 1.f / s : 0.f;
  if (c0 >= 0) Pval[(size_t)row * ADJ_CAP + lane] = e0 * inv;
  if (c1 >= 0) Pval[(size_t)row * ADJ_CAP + lane + 64] = e1 * inv;
  if (lane == 0) sA[row] = fmaxf(-demands[row], 0.f);
}

// ---------------- transposed CSR of (adj, Pval): in-edges per column ----------------
__global__ void k_transpose(const int* __restrict__ adj_idx, const int* __restrict__ adj_cnt,
                            const float* __restrict__ Pval, int* __restrict__ tcnt,
                            int* __restrict__ tsrc, float* __restrict__ tval) {
  int row = blockIdx.x;  // b*N+i
  int lane = threadIdx.x;
  int cnt = adj_cnt[row];
  int base = row & ~(N_ - 1);  // b*N
  for (int t = lane; t < cnt; t += 64) {
    int j = adj_idx[(size_t)row * ADJ_CAP + t];
    int col = base + j;
    int pos = atomicAdd(&tcnt[col], 1);
    if (pos < ADJ_CAP) {
      tsrc[(size_t)col * ADJ_CAP + pos] = row;  // global source row
      tval[(size_t)col * ADJ_CAP + pos] = Pval[(size_t)row * ADJ_CAP + t];
    }
  }
}

// ---------------- one MCF iteration: s_out[j] = relu(sum_i P[i][j] s_in[i] - d[j]) ----
__global__ void k_mcf_iter(const int* __restrict__ tcnt, const int* __restrict__ tsrc,
                           const float* __restrict__ tval, const float* __restrict__ demands,
                           const float* __restrict__ s_in, float* __restrict__ s_out) {
  int j = blockIdx.x * 64 + threadIdx.x;  // 0..B*N-1
  int cnt = tcnt[j];
  const int* src = tsrc + (size_t)j * ADJ_CAP;
  const float* val = tval + (size_t)j * ADJ_CAP;
  float c = 0.f;
  #pragma unroll 4
  for (int t = 0; t < cnt; t++) c += val[t] * s_in[src[t]];
  s_out[j] = fmaxf(c - demands[j], 0.f);
}

// ---------------- flow cost + dual recurrence per adjacency edge ----------------
__global__ void k_flowdual(const int* __restrict__ adj_idx, const int* __restrict__ adj_cnt,
                           const float* __restrict__ Pval, const float* __restrict__ s,
                           const float* __restrict__ dv, float* accum) {
  int tid = threadIdx.x;  // 256
  int lane = tid & 63, w = tid >> 6;
  int row0 = blockIdx.x * 8;
  float fc = 0.f, dc = 0.f;
  for (int rr = w; rr < 8; rr += 4) {
    int row = row0 + rr;
    int b = row >> 11, i = row & (N_ - 1);
    int cnt = adj_cnt[row];
    float si = s[row], dvi = dv[row];
    const int* idx = adj_idx + (size_t)row * ADJ_CAP;
    const float* pv = Pval + (size_t)row * ADJ_CAP;
    for (int t = lane; t < cnt; t += 64) {
      int j = idx[t];
      float f_ij = si * pv[t];
      const int* jidx = adj_idx + (size_t)(b * N_ + j) * ADJ_CAP;
      int jcnt = adj_cnt[b * N_ + j];
      int lo = 0, hi = jcnt, pos = -1;
      while (lo < hi) {
        int mid = (lo + hi) >> 1;
        int v = jidx[mid];
        if (v == i) { pos = mid; break; }
        if (v < i) lo = mid + 1; else hi = mid;
      }
      float f_ji = (pos >= 0) ? s[b * N_ + j] * Pval[(size_t)(b * N_ + j) * ADJ_CAP + pos] : 0.f;
      float fin = f_ij - fminf(f_ij, f_ji);
      fc += fin * fin;
      float dd = dvi - dv[b * N_ + j];
      float y = 0.f, m = 0.f;
      #pragma unroll
      for (int q = 0; q < 10; q++) {
        float g = 2.f * y - dd;
        m = 0.9f * m + g;
        y = fmaxf(y - 0.1f * m, 0.f);
      }
      dc += y * y - dd * y;
    }
  }
  fc = wave_sum(fc); dc = wave_sum(dc);
  __shared__ float FB[4], DB[4];
  if (lane == 0) { FB[w] = fc; DB[w] = dc; }
  __syncthreads();
  if (tid == 0) {
    int b = row0 >> 11;
    atomicAdd(&accum[b], FB[0] + FB[1] + FB[2] + FB[3]);
    atomicAdd(&accum[2 + b], DB[0] + DB[1] + DB[2] + DB[3]);
  }
}

// ---------------- finalize ----------------
__global__ void k_fin(const float* accum, float* out) {
  int b = threadIdx.x;
  if (b < B_) out[b] = accum[b] - accum[2 + b] + accum[4 + b];
}

extern "C" void kernel_launch(void* const* d_in, const int* in_sizes, int n_in,
                              void* d_out, int out_size, void* d_ws, size_t ws_size,
                              hipStream_t stream) {
  const float* feat    = (const float*)d_in[0];
  const float* emb     = (const float*)d_in[1];
  const float* demands = (const float*)d_in[2];
  // d_in[3] (adj) == neighborhoods[0]; not read.
  const float* nbhd    = (const float*)d_in[4];
  const float* enc_W0  = (const float*)d_in[5];
  const float* enc_b0  = (const float*)d_in[6];
  const float* enc_W1  = (const float*)d_in[7];
  const float* enc_b1  = (const float*)d_in[8];
  const float* attn_W  = (const float*)d_in[9];
  const float* a_src   = (const float*)d_in[10];
  const float* a_dst   = (const float*)d_in[11];
  const float* nbr_q   = (const float*)d_in[12];
  const float* gru_W   = (const float*)d_in[13];
  const float* gru_U   = (const float*)d_in[14];
  const float* gru_b   = (const float*)d_in[15];
  const float* dec_W0  = (const float*)d_in[16];
  const float* dec_b0  = (const float*)d_in[17];
  const float* dec_W1  = (const float*)d_in[18];
  const float* dec_b1  = (const float*)d_in[19];
  const float* dual_W0 = (const float*)d_in[20];
  const float* dual_b0 = (const float*)d_in[21];
  const float* dual_W1 = (const float*)d_in[22];
  const float* dual_b1 = (const float*)d_in[23];
  float* out = (float*)d_out;

  char* ws = (char*)d_ws;
  size_t off = 0;
  auto alloc = [&](size_t bytes) { char* p = ws + off; off += (bytes + 255) & ~(size_t)255; return p; };
  int*   adj_idx = (int*)  alloc((size_t)B_ * N_ * ADJ_CAP * 4);
  int*   adj_cnt = (int*)  alloc((size_t)B_ * N_ * 4);
  int*   a2_idx  = (int*)  alloc((size_t)B_ * N_ * A2_CAP * 4);
  int*   a2_cnt  = (int*)  alloc((size_t)B_ * N_ * 4);
  float* h       = (float*)alloc((size_t)B_ * N_ * 64 * 4);
  float* z       = (float*)alloc((size_t)2 * B_ * N_ * 64 * 4);
  float* ssrc    = (float*)alloc((size_t)2 * B_ * N_ * 4);
  float* sdst    = (float*)alloc((size_t)2 * B_ * N_ * 4);
  float* aggs    = (float*)alloc((size_t)B_ * N_ * 2 * 64 * 4);
  float* nw      = (float*)alloc((size_t)B_ * N_ * 4);
  float* dv      = (float*)alloc((size_t)B_ * N_ * 4);
  float* Pval    = (float*)alloc((size_t)B_ * N_ * ADJ_CAP * 4);
  int*   tcnt    = (int*)  alloc((size_t)B_ * N_ * 4);
  int*   tsrc    = (int*)  alloc((size_t)B_ * N_ * ADJ_CAP * 4);
  float* tval    = (float*)alloc((size_t)B_ * N_ * ADJ_CAP * 4);
  float* sA      = (float*)alloc((size_t)B_ * N_ * 4);
  float* sB      = (float*)alloc((size_t)B_ * N_ * 4);
  float* accum   = (float*)alloc(8 * 4);

  k_zero<<<(B_ * N_ + 255) / 256, 256, 0, stream>>>(tcnt, accum);
  k_csr<<<(2 * B_ * N_) / 4, 256, 0, stream>>>(nbhd, adj_idx, adj_cnt, a2_idx, a2_cnt);
  k_enc<<<(B_ * N_) / ROWS, 64, 0, stream>>>(emb, feat, enc_W0, enc_b0, enc_W1, enc_b1, h);
  for (int layer = 0; layer < 2; layer++) {
    k_z<<<(B_ * N_) / ROWS, 128, 0, stream>>>(h, attn_W, a_src, a_dst, z, ssrc, sdst);
    k_agg<<<B_ * N_ * 2, 256, 0, stream>>>(adj_idx, adj_cnt, a2_idx, a2_cnt, z, ssrc, sdst, aggs);
    k_comb<<<(B_ * N_) / ROWS, 128, 0, stream>>>(aggs, nbr_q, gru_W, gru_U, gru_b, h);
  }
  k_dec<<<(B_ * N_) / ROWS, 64, 0, stream>>>(h, dec_W0, dec_b0, dec_W1, dec_b1,
                                             dual_W0, dual_b0, dual_W1, dual_b1,
                                             demands, nw, dv, accum);
  k_prop<<<B_ * N_, 64, 0, stream>>>(adj_idx, adj_cnt, nw, demands, Pval, sA);
  k_transpose<<<B_ * N_, 64, 0, stream>>>(adj_idx, adj_cnt, Pval, tcnt, tsrc, tval);
  // s_1 = relu(-d) in sA; 9 more iterations -> s_10 ends in sB
  for (int it = 0; it < 9; it++) {
    float* sin  = (it & 1) ? sB : sA;
    float* sout = (it & 1) ? sA : sB;
    k_mcf_iter<<<(B_ * N_) / 64, 64, 0, stream>>>(tcnt, tsrc, tval, demands, sin, sout);
  }
  k_flowdual<<<(B_ * N_) / 8, 256, 0, stream>>>(adj_idx, adj_cnt, Pval, sB, dv, accum);
  k_fin<<<1, 64, 0, stream>>>(accum, out);
}

// Round 4
// 416.291 us; speedup vs baseline: 2.3219x; 1.0916x over previous
//
#include <hip/hip_runtime.h>

#define B_ 2
#define N_ 2048
#define E_ 64
#define FIN_ 18
#define ADJ_CAP 128
#define A2_CAP 1024
#define ROWS 8

__device__ __forceinline__ float wave_sum(float v) {
  #pragma unroll
  for (int o = 32; o > 0; o >>= 1) v += __shfl_xor(v, o);
  return v;
}
__device__ __forceinline__ float wave_max(float v) {
  #pragma unroll
  for (int o = 32; o > 0; o >>= 1) v = fmaxf(v, __shfl_xor(v, o));
  return v;
}
__device__ __forceinline__ void grp_reduce(float4& a) {
  #pragma unroll
  for (int o = 16; o <= 32; o <<= 1) {
    a.x += __shfl_xor(a.x, o); a.y += __shfl_xor(a.y, o);
    a.z += __shfl_xor(a.z, o); a.w += __shfl_xor(a.w, o);
  }
}

// ---------------- build CSR from neighborhoods (K=2,B,N,N); also zero accum ----------
// float4 loads, order-preserving 4-ballot compaction (adj_idx stays sorted).
__global__ void k_csr(const float* __restrict__ nbhd, int* __restrict__ adj_idx,
                      int* __restrict__ adj_cnt, int* __restrict__ a2_idx,
                      int* __restrict__ a2_cnt, float* __restrict__ accum) {
  int wid = blockIdx.x * 4 + (threadIdx.x >> 6);  // 0 .. 2*B*N-1
  int lane = threadIdx.x & 63;
  if (wid == 0 && lane < 8) accum[lane] = 0.f;
  int k = wid / (B_ * N_);
  int rem = wid - k * (B_ * N_);  // b*N + i
  const float* row = nbhd + ((size_t)k * (B_ * N_) + rem) * N_;
  int cap = (k == 0) ? ADJ_CAP : A2_CAP;
  int* idx = ((k == 0) ? adj_idx : a2_idx) + (size_t)rem * cap;
  int* cntp = ((k == 0) ? adj_cnt : a2_cnt) + rem;
  int cnt = 0;
  unsigned long long below = (1ull << lane) - 1ull;
  for (int j0 = 0; j0 < N_; j0 += 256) {
    float4 v = ((const float4*)(row + j0))[lane];
    bool p0 = v.x > 0.f, p1 = v.y > 0.f, p2 = v.z > 0.f, p3 = v.w > 0.f;
    unsigned long long b0 = __ballot(p0), b1 = __ballot(p1),
                       b2 = __ballot(p2), b3 = __ballot(p3);
    int pos = cnt + __popcll(b0 & below) + __popcll(b1 & below) +
              __popcll(b2 & below) + __popcll(b3 & below);
    int base_j = j0 + lane * 4;
    if (p0) { if (pos < cap) idx[pos] = base_j;     pos++; }
    if (p1) { if (pos < cap) idx[pos] = base_j + 1; pos++; }
    if (p2) { if (pos < cap) idx[pos] = base_j + 2; pos++; }
    if (p3) { if (pos < cap) idx[pos] = base_j + 3; pos++; }
    cnt += __popcll(b0) + __popcll(b1) + __popcll(b2) + __popcll(b3);
  }
  if (lane == 0) *cntp = (cnt < cap) ? cnt : cap;
}

// ---------------- encoder: h = tanh(tanh(x@W0+b0)@W1+b1) ----------------
__global__ void k_enc(const float* __restrict__ emb, const float* __restrict__ feat,
                      const float* __restrict__ W0, const float* __restrict__ b0,
                      const float* __restrict__ W1, const float* __restrict__ b1,
                      float* __restrict__ h) {
  int j = threadIdx.x;  // 64
  int row0 = blockIdx.x * ROWS;
  __shared__ float X[ROWS][FIN_];
  __shared__ float HID[ROWS][64];
  for (int t = j; t < ROWS * FIN_; t += 64) {
    int r = t / FIN_, d = t % FIN_;
    int row = row0 + r;
    X[r][d] = (d < 16) ? emb[(size_t)row * 16 + d] : feat[(size_t)row * 2 + (d - 16)];
  }
  __syncthreads();
  float acc[ROWS];
  #pragma unroll
  for (int r = 0; r < ROWS; r++) acc[r] = b0[j];
  for (int d = 0; d < FIN_; d++) {
    float w = W0[d * 64 + j];
    #pragma unroll
    for (int r = 0; r < ROWS; r++) acc[r] += X[r][d] * w;
  }
  #pragma unroll
  for (int r = 0; r < ROWS; r++) HID[r][j] = tanhf(acc[r]);
  __syncthreads();
  float acc2[ROWS];
  #pragma unroll
  for (int r = 0; r < ROWS; r++) acc2[r] = b1[j];
  for (int d = 0; d < 64; d++) {
    float w = W1[d * 64 + j];
    #pragma unroll
    for (int r = 0; r < ROWS; r++) acc2[r] += HID[r][d] * w;
  }
  #pragma unroll
  for (int r = 0; r < ROWS; r++) h[(size_t)(row0 + r) * 64 + j] = tanhf(acc2[r]);
}

// ---------------- z = h@attn_W[head], s_src, s_dst (interleaved float2) -------------
__global__ void k_z(const float* __restrict__ h, const float* __restrict__ attn_W,
                    const float* __restrict__ a_src, const float* __restrict__ a_dst,
                    float* __restrict__ z, float* __restrict__ ssrc2, float* __restrict__ sdst2) {
  int tid = threadIdx.x;  // 128
  int head = tid >> 6, j = tid & 63;
  int row0 = blockIdx.x * ROWS;
  __shared__ float HR[ROWS][64];
  for (int t = tid; t < ROWS * 64; t += 128) HR[t >> 6][t & 63] = h[(size_t)row0 * 64 + t];
  __syncthreads();
  float acc[ROWS];
  #pragma unroll
  for (int r = 0; r < ROWS; r++) acc[r] = 0.f;
  const float* W = attn_W + head * 64 * 64;
  for (int d = 0; d < 64; d++) {
    float w = W[d * 64 + j];
    #pragma unroll
    for (int r = 0; r < ROWS; r++) acc[r] += HR[r][d] * w;
  }
  float as = a_src[head * 64 + j], ad = a_dst[head * 64 + j];
  #pragma unroll
  for (int r = 0; r < ROWS; r++) {
    float zv = acc[r];
    z[((size_t)head * (B_ * N_) + row0 + r) * 64 + j] = zv;
    float rs = wave_sum(zv * as);
    float rd = wave_sum(zv * ad);
    if (j == 0) {
      ssrc2[(size_t)(row0 + r) * 2 + head] = rs;
      sdst2[(size_t)(row0 + r) * 2 + head] = rd;
    }
  }
}

// ---------------- adj aggregation: one wave per row, no LDS, no barriers ------------
__global__ __launch_bounds__(64) void k_agg_adj(
    const int* __restrict__ adj_idx, const int* __restrict__ adj_cnt,
    const float* __restrict__ z, const float* __restrict__ ssrc2,
    const float* __restrict__ sdst2, float* __restrict__ aggs) {
  int row = blockIdx.x;
  int lane = threadIdx.x;
  int b = row >> 11;
  int cnt = adj_cnt[row];
  const int* idx = adj_idx + (size_t)row * ADJ_CAP;
  float2 ss = ((const float2*)ssrc2)[row];
  const float2* sd = (const float2*)sdst2 + (size_t)b * N_;
  int col0 = 0, col1 = 0;
  float e00 = 0.f, e10 = 0.f, e01 = 0.f, e11 = 0.f;
  if (lane < cnt) {
    col0 = idx[lane]; float2 s = sd[col0];
    e00 = __expf(tanhf(ss.x + s.x)); e10 = __expf(tanhf(ss.y + s.y));
  }
  if (lane + 64 < cnt) {
    col1 = idx[lane + 64]; float2 s = sd[col1];
    e01 = __expf(tanhf(ss.x + s.x)); e11 = __expf(tanhf(ss.y + s.y));
  }
  float tot0 = wave_sum(e00 + e01), tot1 = wave_sum(e10 + e11);
  float inv0 = (tot0 > 0.f) ? 1.f / tot0 : 0.f;
  float inv1 = (tot1 > 0.f) ? 1.f / tot1 : 0.f;
  const float* z0 = z + (size_t)b * N_ * 64;
  const float* z1 = z + ((size_t)(B_ * N_) + b * N_) * 64;
  int g = lane >> 4, li = lane & 15;
  float4 a0 = {0.f, 0.f, 0.f, 0.f}, a1 = {0.f, 0.f, 0.f, 0.f};
  for (int j0 = 0; j0 < 64; j0 += 4) {
    if (j0 >= cnt) break;
    int j = j0 + g;
    int c = __shfl(col0, j);
    float e0 = __shfl(e00, j), e1 = __shfl(e10, j);
    if (j < cnt) {
      float4 v0 = ((const float4*)(z0 + (size_t)c * 64))[li];
      float4 v1 = ((const float4*)(z1 + (size_t)c * 64))[li];
      a0.x += e0 * v0.x; a0.y += e0 * v0.y; a0.z += e0 * v0.z; a0.w += e0 * v0.w;
      a1.x += e1 * v1.x; a1.y += e1 * v1.y; a1.z += e1 * v1.z; a1.w += e1 * v1.w;
    }
  }
  if (cnt > 64) {
    for (int j0 = 0; j0 < 64; j0 += 4) {
      if (64 + j0 >= cnt) break;
      int j = j0 + g;
      int c = __shfl(col1, j);
      float e0 = __shfl(e01, j), e1 = __shfl(e11, j);
      if (64 + j < cnt) {
        float4 v0 = ((const float4*)(z0 + (size_t)c * 64))[li];
        float4 v1 = ((const float4*)(z1 + (size_t)c * 64))[li];
        a0.x += e0 * v0.x; a0.y += e0 * v0.y; a0.z += e0 * v0.z; a0.w += e0 * v0.w;
        a1.x += e1 * v1.x; a1.y += e1 * v1.y; a1.z += e1 * v1.z; a1.w += e1 * v1.w;
      }
    }
  }
  grp_reduce(a0); grp_reduce(a1);
  if (g == 0) {
    float4 o;
    o.x = tanhf(0.5f * (a0.x * inv0 + a1.x * inv1));
    o.y = tanhf(0.5f * (a0.y * inv0 + a1.y * inv1));
    o.z = tanhf(0.5f * (a0.z * inv0 + a1.z * inv1));
    o.w = tanhf(0.5f * (a0.w * inv0 + a1.w * inv1));
    ((float4*)(aggs + ((size_t)row * 2 + 0) * 64))[li] = o;
  }
}

// ---------------- a2 aggregation: 256 thr, registers + shfl, single barrier ---------
__global__ __launch_bounds__(256) void k_agg_a2(
    const int* __restrict__ a2_idx, const int* __restrict__ a2_cnt,
    const float* __restrict__ z, const float* __restrict__ ssrc2,
    const float* __restrict__ sdst2, float* __restrict__ aggs) {
  int row = blockIdx.x;
  int tid = threadIdx.x;
  int w = tid >> 6, lane = tid & 63;
  int b = row >> 11;
  int cnt = a2_cnt[row];
  const int* idx = a2_idx + (size_t)row * A2_CAP;
  float2 ss = ((const float2*)ssrc2)[row];
  const float2* sd = (const float2*)sdst2 + (size_t)b * N_;
  int colr[4]; float e0r[4], e1r[4];
  float s0 = 0.f, s1 = 0.f;
  #pragma unroll
  for (int c = 0; c < 4; c++) {
    int t = c * 256 + tid;
    colr[c] = 0; e0r[c] = 0.f; e1r[c] = 0.f;
    if (t < cnt) {
      int cc = idx[t]; colr[c] = cc;
      float2 s = sd[cc];
      e0r[c] = __expf(tanhf(ss.x + s.x));
      e1r[c] = __expf(tanhf(ss.y + s.y));
      s0 += e0r[c]; s1 += e1r[c];
    }
  }
  s0 = wave_sum(s0); s1 = wave_sum(s1);
  __shared__ float RED[2][4];
  __shared__ float WS0[4][64], WS1[4][64];
  if (lane == 0) { RED[0][w] = s0; RED[1][w] = s1; }
  const float* z0 = z + (size_t)b * N_ * 64;
  const float* z1 = z + ((size_t)(B_ * N_) + b * N_) * 64;
  int g = lane >> 4, li = lane & 15;
  float4 a0 = {0.f, 0.f, 0.f, 0.f}, a1 = {0.f, 0.f, 0.f, 0.f};
  #pragma unroll
  for (int c = 0; c < 4; c++) {
    int base = c * 256 + w * 64;
    if (base >= cnt) break;
    for (int j0 = 0; j0 < 64; j0 += 4) {
      if (base + j0 >= cnt) break;
      int j = j0 + g;
      int col = __shfl(colr[c], j);
      float e0 = __shfl(e0r[c], j), e1 = __shfl(e1r[c], j);
      if (base + j < cnt) {
        float4 v0 = ((const float4*)(z0 + (size_t)col * 64))[li];
        float4 v1 = ((const float4*)(z1 + (size_t)col * 64))[li];
        a0.x += e0 * v0.x; a0.y += e0 * v0.y; a0.z += e0 * v0.z; a0.w += e0 * v0.w;
        a1.x += e1 * v1.x; a1.y += e1 * v1.y; a1.z += e1 * v1.z; a1.w += e1 * v1.w;
      }
    }
  }
  grp_reduce(a0); grp_reduce(a1);
  if (g == 0) {
    ((float4*)WS0[w])[li] = a0;
    ((float4*)WS1[w])[li] = a1;
  }
  __syncthreads();
  if (tid < 64) {
    float tot0 = RED[0][0] + RED[0][1] + RED[0][2] + RED[0][3];
    float tot1 = RED[1][0] + RED[1][1] + RED[1][2] + RED[1][3];
    float inv0 = (tot0 > 0.f) ? 1.f / tot0 : 0.f;
    float inv1 = (tot1 > 0.f) ? 1.f / tot1 : 0.f;
    float r0 = WS0[0][tid] + WS0[1][tid] + WS0[2][tid] + WS0[3][tid];
    float r1 = WS1[0][tid] + WS1[1][tid] + WS1[2][tid] + WS1[3][tid];
    aggs[((size_t)row * 2 + 1) * 64 + tid] = tanhf(0.5f * (r0 * inv0 + r1 * inv1));
  }
}

// ---------------- nbr-softmax combine + GRU ----------------
__global__ void k_comb(const float* __restrict__ aggs, const float* __restrict__ nbr_q,
                       const float* __restrict__ gru_W, const float* __restrict__ gru_U,
                       const float* __restrict__ gru_b, float* __restrict__ h) {
  int tid = threadIdx.x;  // 128
  int w = tid >> 6, j = tid & 63;
  int row0 = blockIdx.x * ROWS;
  __shared__ float NXT[ROWS][64], HROW[ROWS][64], RG[ROWS][64], ZG[ROWS][64];
  for (int t = tid; t < ROWS * 64; t += 128) HROW[t >> 6][t & 63] = h[(size_t)row0 * 64 + t];
  float q = nbr_q[j];
  for (int r = w * (ROWS / 2); r < (w + 1) * (ROWS / 2); r++) {
    float a0 = aggs[((size_t)(row0 + r) * 2 + 0) * 64 + j];
    float a1 = aggs[((size_t)(row0 + r) * 2 + 1) * 64 + j];
    float t0 = tanhf(wave_sum(a0 * q));
    float t1 = tanhf(wave_sum(a1 * q));
    float mx = fmaxf(t0, t1);
    float e0 = __expf(t0 - mx), e1 = __expf(t1 - mx);
    float inv = 1.f / (e0 + e1);
    NXT[r][j] = (e0 * a0 + e1 * a1) * inv;
  }
  __syncthreads();
  {
    float acc[ROWS];
    #pragma unroll
    for (int r = 0; r < ROWS; r++) acc[r] = gru_b[tid];
    for (int d = 0; d < 64; d++) {
      float wW = gru_W[d * 192 + tid];
      float wU = gru_U[d * 192 + tid];
      #pragma unroll
      for (int r = 0; r < ROWS; r++) acc[r] += NXT[r][d] * wW + HROW[r][d] * wU;
    }
    #pragma unroll
    for (int r = 0; r < ROWS; r++) {
      float zr = 1.f / (1.f + __expf(-acc[r]));
      if (tid < 64) ZG[r][tid] = zr; else RG[r][tid - 64] = zr;
    }
  }
  __syncthreads();
  if (tid < 64) {
    int col = 128 + tid;
    float acc[ROWS];
    #pragma unroll
    for (int r = 0; r < ROWS; r++) acc[r] = gru_b[col];
    for (int d = 0; d < 64; d++) {
      float wW = gru_W[d * 192 + col];
      float wU = gru_U[d * 192 + col];
      #pragma unroll
      for (int r = 0; r < ROWS; r++) acc[r] += NXT[r][d] * wW + (RG[r][d] * HROW[r][d]) * wU;
    }
    #pragma unroll
    for (int r = 0; r < ROWS; r++) {
      float ht = tanhf(acc[r]);
      float zg = ZG[r][tid];
      h[(size_t)(row0 + r) * 64 + tid] = (1.f - zg) * HROW[r][tid] + zg * ht;
    }
  }
}

// ---------------- decoder + dual heads (+ dual_demand) ----------------
__global__ void k_dec(const float* __restrict__ h, const float* __restrict__ dW0,
                      const float* __restrict__ db0, const float* __restrict__ dW1,
                      const float* __restrict__ db1, const float* __restrict__ uW0,
                      const float* __restrict__ ub0, const float* __restrict__ uW1,
                      const float* __restrict__ ub1, const float* __restrict__ demands,
                      float* __restrict__ nw, float* __restrict__ dv, float* accum) {
  int j = threadIdx.x;  // 64
  int row0 = blockIdx.x * ROWS;
  __shared__ float HROW[ROWS][64];
  for (int t = j; t < ROWS * 64; t += 64) HROW[t >> 6][t & 63] = h[(size_t)row0 * 64 + t];
  __syncthreads();
  float hd[ROWS], hu[ROWS];
  #pragma unroll
  for (int r = 0; r < ROWS; r++) { hd[r] = db0[j]; hu[r] = ub0[j]; }
  for (int d = 0; d < 64; d++) {
    float w0 = dW0[d * 64 + j], u0 = uW0[d * 64 + j];
    #pragma unroll
    for (int r = 0; r < ROWS; r++) { hd[r] += HROW[r][d] * w0; hu[r] += HROW[r][d] * u0; }
  }
  float w1 = dW1[j], u1 = uW1[j];
  float ddl = 0.f;
  #pragma unroll
  for (int r = 0; r < ROWS; r++) {
    float a = wave_sum(tanhf(hd[r]) * w1);
    float bb = wave_sum(tanhf(hu[r]) * u1);
    if (j == 0) {
      int row = row0 + r;
      float nwv = a + db1[0], dvv = bb + ub1[0];
      nw[row] = nwv; dv[row] = dvv;
      ddl += dvv * demands[row];
    }
  }
  if (j == 0) atomicAdd(&accum[4 + (row0 >> 11)], ddl);
}

// ---------------- sparse row-softmax P (+ s_1 init, + tcnt zero) ----------------
__global__ void k_prop(const int* __restrict__ adj_idx, const int* __restrict__ adj_cnt,
                       const float* __restrict__ nw, const float* __restrict__ demands,
                       float* __restrict__ Pval, float* __restrict__ sA,
                       int* __restrict__ tcnt) {
  int row = blockIdx.x;
  int lane = threadIdx.x;
  int b = row >> 11;
  int cnt = adj_cnt[row];
  const int* idx = adj_idx + (size_t)row * ADJ_CAP;
  int c0 = (lane < cnt) ? idx[lane] : -1;
  int c1 = (lane + 64 < cnt) ? idx[lane + 64] : -1;
  float v0 = (c0 >= 0) ? nw[b * N_ + c0] : -1e30f;
  float v1 = (c1 >= 0) ? nw[b * N_ + c1] : -1e30f;
  float m = wave_max(fmaxf(v0, v1));
  float e0 = (c0 >= 0) ? __expf(v0 - m) : 0.f;
  float e1 = (c1 >= 0) ? __expf(v1 - m) : 0.f;
  float s = wave_sum(e0 + e1);
  float inv = (s > 0.f) ? 1.f / s : 0.f;
  if (c0 >= 0) Pval[(size_t)row * ADJ_CAP + lane] = e0 * inv;
  if (c1 >= 0) Pval[(size_t)row * ADJ_CAP + lane + 64] = e1 * inv;
  if (lane == 0) sA[row] = fmaxf(-demands[row], 0.f);
  if (lane == 63) tcnt[row] = 0;
}

// ---------------- transposed CSR of (adj, Pval): in-edges per column ----------------
__global__ void k_transpose(const int* __restrict__ adj_idx, const int* __restrict__ adj_cnt,
                            const float* __restrict__ Pval, int* __restrict__ tcnt,
                            int* __restrict__ tsrc, float* __restrict__ tval) {
  int row = blockIdx.x;  // b*N+i
  int lane = threadIdx.x;
  int cnt = adj_cnt[row];
  int base = row & ~(N_ - 1);  // b*N
  for (int t = lane; t < cnt; t += 64) {
    int j = adj_idx[(size_t)row * ADJ_CAP + t];
    int col = base + j;
    int pos = atomicAdd(&tcnt[col], 1);
    if (pos < ADJ_CAP) {
      tsrc[(size_t)col * ADJ_CAP + pos] = row;  // global source row
      tval[(size_t)col * ADJ_CAP + pos] = Pval[(size_t)row * ADJ_CAP + t];
    }
  }
}

// ---------------- one MCF iteration: s_out[j] = relu(sum_i P[i][j] s_in[i] - d[j]) ----
__global__ void k_mcf_iter(const int* __restrict__ tcnt, const int* __restrict__ tsrc,
                           const float* __restrict__ tval, const float* __restrict__ demands,
                           const float* __restrict__ s_in, float* __restrict__ s_out) {
  int j = blockIdx.x * 64 + threadIdx.x;  // 0..B*N-1
  int cnt = tcnt[j];
  const int* src = tsrc + (size_t)j * ADJ_CAP;
  const float* val = tval + (size_t)j * ADJ_CAP;
  float c = 0.f;
  int c4 = cnt >> 2;
  for (int q = 0; q < c4; q++) {
    int4 s4 = ((const int4*)src)[q];
    float4 v4 = ((const float4*)val)[q];
    c += v4.x * s_in[s4.x] + v4.y * s_in[s4.y] + v4.z * s_in[s4.z] + v4.w * s_in[s4.w];
  }
  for (int t = c4 * 4; t < cnt; t++) c += val[t] * s_in[src[t]];
  s_out[j] = fmaxf(c - demands[j], 0.f);
}

// ---------------- flow cost + dual recurrence; 4 rows per wave (16-lane groups) -----
__global__ __launch_bounds__(256) void k_flowdual(
    const int* __restrict__ adj_idx, const int* __restrict__ adj_cnt,
    const float* __restrict__ Pval, const float* __restrict__ s,
    const float* __restrict__ dv, float* accum) {
  int tid = threadIdx.x;  // 256
  int lane = tid & 63, w = tid >> 6;
  int r16 = lane >> 4, e = lane & 15;
  int row = blockIdx.x * 16 + w * 4 + r16;  // grid = B*N/16; same batch per block
  int b = row >> 11, i = row & (N_ - 1);
  int cnt = adj_cnt[row];
  float si = s[row], dvi = dv[row];
  const int* idx = adj_idx + (size_t)row * ADJ_CAP;
  const float* pv = Pval + (size_t)row * ADJ_CAP;
  float fc = 0.f, dc = 0.f;
  for (int t = e; t < cnt; t += 16) {
    int j = idx[t];
    float f_ij = si * pv[t];
    const int* jidx = adj_idx + (size_t)(b * N_ + j) * ADJ_CAP;
    int jcnt = adj_cnt[b * N_ + j];
    int lo = 0, hi = jcnt, pos = -1;
    while (lo < hi) {
      int mid = (lo + hi) >> 1;
      int v = jidx[mid];
      if (v == i) { pos = mid; break; }
      if (v < i) lo = mid + 1; else hi = mid;
    }
    float f_ji = (pos >= 0) ? s[b * N_ + j] * Pval[(size_t)(b * N_ + j) * ADJ_CAP + pos] : 0.f;
    float fin = f_ij - fminf(f_ij, f_ji);
    fc += fin * fin;
    float dd = dvi - dv[b * N_ + j];
    float y = 0.f, m = 0.f;
    #pragma unroll
    for (int q = 0; q < 10; q++) {
      float g = 2.f * y - dd;
      m = 0.9f * m + g;
      y = fmaxf(y - 0.1f * m, 0.f);
    }
    dc += y * y - dd * y;
  }
  fc = wave_sum(fc); dc = wave_sum(dc);
  __shared__ float FB[4], DB[4];
  if (lane == 0) { FB[w] = fc; DB[w] = dc; }
  __syncthreads();
  if (tid == 0) {
    int bb = (blockIdx.x * 16) >> 11;
    atomicAdd(&accum[bb], FB[0] + FB[1] + FB[2] + FB[3]);
    atomicAdd(&accum[2 + bb], DB[0] + DB[1] + DB[2] + DB[3]);
  }
}

// ---------------- finalize ----------------
__global__ void k_fin(const float* accum, float* out) {
  int b = threadIdx.x;
  if (b < B_) out[b] = accum[b] - accum[2 + b] + accum[4 + b];
}

extern "C" void kernel_launch(void* const* d_in, const int* in_sizes, int n_in,
                              void* d_out, int out_size, void* d_ws, size_t ws_size,
                              hipStream_t stream) {
  const float* feat    = (const float*)d_in[0];
  const float* emb     = (const float*)d_in[1];
  const float* demands = (const float*)d_in[2];
  // d_in[3] (adj) == neighborhoods[0]; not read.
  const float* nbhd    = (const float*)d_in[4];
  const float* enc_W0  = (const float*)d_in[5];
  const float* enc_b0  = (const float*)d_in[6];
  const float* enc_W1  = (const float*)d_in[7];
  const float* enc_b1  = (const float*)d_in[8];
  const float* attn_W  = (const float*)d_in[9];
  const float* a_src   = (const float*)d_in[10];
  const float* a_dst   = (const float*)d_in[11];
  const float* nbr_q   = (const float*)d_in[12];
  const float* gru_W   = (const float*)d_in[13];
  const float* gru_U   = (const float*)d_in[14];
  const float* gru_b   = (const float*)d_in[15];
  const float* dec_W0  = (const float*)d_in[16];
  const float* dec_b0  = (const float*)d_in[17];
  const float* dec_W1  = (const float*)d_in[18];
  const float* dec_b1  = (const float*)d_in[19];
  const float* dual_W0 = (const float*)d_in[20];
  const float* dual_b0 = (const float*)d_in[21];
  const float* dual_W1 = (const float*)d_in[22];
  const float* dual_b1 = (const float*)d_in[23];
  float* out = (float*)d_out;

  char* ws = (char*)d_ws;
  size_t off = 0;
  auto alloc = [&](size_t bytes) { char* p = ws + off; off += (bytes + 255) & ~(size_t)255; return p; };
  int*   adj_idx = (int*)  alloc((size_t)B_ * N_ * ADJ_CAP * 4);
  int*   adj_cnt = (int*)  alloc((size_t)B_ * N_ * 4);
  int*   a2_idx  = (int*)  alloc((size_t)B_ * N_ * A2_CAP * 4);
  int*   a2_cnt  = (int*)  alloc((size_t)B_ * N_ * 4);
  float* h       = (float*)alloc((size_t)B_ * N_ * 64 * 4);
  float* z       = (float*)alloc((size_t)2 * B_ * N_ * 64 * 4);
  float* ssrc2   = (float*)alloc((size_t)2 * B_ * N_ * 4);
  float* sdst2   = (float*)alloc((size_t)2 * B_ * N_ * 4);
  float* aggs    = (float*)alloc((size_t)B_ * N_ * 2 * 64 * 4);
  float* nw      = (float*)alloc((size_t)B_ * N_ * 4);
  float* dv      = (float*)alloc((size_t)B_ * N_ * 4);
  float* Pval    = (float*)alloc((size_t)B_ * N_ * ADJ_CAP * 4);
  int*   tcnt    = (int*)  alloc((size_t)B_ * N_ * 4);
  int*   tsrc    = (int*)  alloc((size_t)B_ * N_ * ADJ_CAP * 4);
  float* tval    = (float*)alloc((size_t)B_ * N_ * ADJ_CAP * 4);
  float* sA      = (float*)alloc((size_t)B_ * N_ * 4);
  float* sB      = (float*)alloc((size_t)B_ * N_ * 4);
  float* accum   = (float*)alloc(8 * 4);

  k_csr<<<(2 * B_ * N_) / 4, 256, 0, stream>>>(nbhd, adj_idx, adj_cnt, a2_idx, a2_cnt, accum);
  k_enc<<<(B_ * N_) / ROWS, 64, 0, stream>>>(emb, feat, enc_W0, enc_b0, enc_W1, enc_b1, h);
  for (int layer = 0; layer < 2; layer++) {
    k_z<<<(B_ * N_) / ROWS, 128, 0, stream>>>(h, attn_W, a_src, a_dst, z, ssrc2, sdst2);
    k_agg_adj<<<B_ * N_, 64, 0, stream>>>(adj_idx, adj_cnt, z, ssrc2, sdst2, aggs);
    k_agg_a2<<<B_ * N_, 256, 0, stream>>>(a2_idx, a2_cnt, z, ssrc2, sdst2, aggs);
    k_comb<<<(B_ * N_) / ROWS, 128, 0, stream>>>(aggs, nbr_q, gru_W, gru_U, gru_b, h);
  }
  k_dec<<<(B_ * N_) / ROWS, 64, 0, stream>>>(h, dec_W0, dec_b0, dec_W1, dec_b1,
                                             dual_W0, dual_b0, dual_W1, dual_b1,
                                             demands, nw, dv, accum);
  k_prop<<<B_ * N_, 64, 0, stream>>>(adj_idx, adj_cnt, nw, demands, Pval, sA, tcnt);
  k_transpose<<<B_ * N_, 64, 0, stream>>>(adj_idx, adj_cnt, Pval, tcnt, tsrc, tval);
  // s_1 = relu(-d) in sA; 9 more iterations -> s_10 ends in sB
  for (int it = 0; it < 9; it++) {
    float* sin  = (it & 1) ? sB : sA;
    float* sout = (it & 1) ? sA : sB;
    k_mcf_iter<<<(B_ * N_) / 64, 64, 0, stream>>>(tcnt, tsrc, tval, demands, sin, sout);
  }
  k_flowdual<<<(B_ * N_) / 16, 256, 0, stream>>>(adj_idx, adj_cnt, Pval, sB, dv, accum);
  k_fin<<<1, 64, 0, stream>>>(accum, out);
}